// Round 1
// baseline (2560.379 us; speedup 1.0000x reference)
//
#include <hip/hip_runtime.h>
#include <math.h>

// Problem constants: B=2, T=2048, D=768, H=12, HS=64, FF=3072, HALF=1536
#define TDIM 2048
#define DDIM 768
#define NH   12
#define HSZ  64
#define NROWS 4096            // B*T
#define EPSV 1e-8f
#define SCALE 0.03608439182435161f   // 768^-0.5  (ref scales by D, not HS)

// ---------------- RMSNorm: out = g * x / (||x||/sqrt(D) + eps) ----------------
__global__ __launch_bounds__(256) void rmsnorm_kernel(
    const float* __restrict__ x, const float* __restrict__ g,
    float* __restrict__ out)
{
    int row = blockIdx.x;
    int tid = threadIdx.x;
    const float* xr = x + (size_t)row * DDIM;
    float v0 = xr[tid], v1 = xr[tid + 256], v2 = xr[tid + 512];
    float s = v0*v0 + v1*v1 + v2*v2;
    #pragma unroll
    for (int off = 32; off > 0; off >>= 1)
        s += __shfl_down(s, off, 64);
    __shared__ float red[4];
    __shared__ float tot;
    if ((tid & 63) == 0) red[tid >> 6] = s;
    __syncthreads();
    if (tid == 0) tot = red[0] + red[1] + red[2] + red[3];
    __syncthreads();
    float rms = sqrtf(tot * (1.0f / DDIM));
    float inv = 1.0f / (rms + EPSV);
    float* orow = out + (size_t)row * DDIM;
    orow[tid]       = g[tid]       * v0 * inv;
    orow[tid + 256] = g[tid + 256] * v1 * inv;
    orow[tid + 512] = g[tid + 512] * v2 * inv;
}

// ---------------- Generic 64x64 tiled fp32 GEMM ----------------
// C[M x N] = A[M x K] * B[K x N] (+bias[col]) (+resid same layout as C)
// B tile pointer = B + blockIdx.x * bstride  (bstride=64 for plain row-major B
// with ldb=N; bstride=K*64 with ldb=64 for per-head weight slices).
// All dims: M%64==0, N%64==0, K%16==0 (true for every call here).
__global__ __launch_bounds__(256) void gemm64(
    const float* __restrict__ A, int lda,
    const float* __restrict__ B, int ldb, int bstride,
    float* __restrict__ C, int ldc, int K,
    const float* __restrict__ bias,
    const float* __restrict__ resid)
{
    __shared__ float As[64][17];   // +1 pad: kills stride-64 bank conflict
    __shared__ float Bs[16][64];
    int tid = threadIdx.x;
    int tx = tid & 15, ty = tid >> 4;
    const float* Ab = A + (size_t)blockIdx.y * 64 * lda;
    const float* Bb = B + (size_t)blockIdx.x * bstride;

    int arow = tid >> 2, acol = (tid & 3) * 4;   // A tile: 64 x 16 via float4
    int brow = tid >> 4, bcol = (tid & 15) * 4;  // B tile: 16 x 64 via float4

    float acc[4][4] = {};
    for (int k0 = 0; k0 < K; k0 += 16) {
        float4 av = *(const float4*)(Ab + (size_t)arow * lda + k0 + acol);
        float4 bv = *(const float4*)(Bb + (size_t)(k0 + brow) * ldb + bcol);
        As[arow][acol+0] = av.x; As[arow][acol+1] = av.y;
        As[arow][acol+2] = av.z; As[arow][acol+3] = av.w;
        *(float4*)&Bs[brow][bcol] = bv;
        __syncthreads();
        #pragma unroll
        for (int kk = 0; kk < 16; kk++) {
            float a0 = As[ty*4+0][kk], a1 = As[ty*4+1][kk];
            float a2 = As[ty*4+2][kk], a3 = As[ty*4+3][kk];
            float b0 = Bs[kk][tx*4+0], b1 = Bs[kk][tx*4+1];
            float b2 = Bs[kk][tx*4+2], b3 = Bs[kk][tx*4+3];
            acc[0][0] += a0*b0; acc[0][1] += a0*b1; acc[0][2] += a0*b2; acc[0][3] += a0*b3;
            acc[1][0] += a1*b0; acc[1][1] += a1*b1; acc[1][2] += a1*b2; acc[1][3] += a1*b3;
            acc[2][0] += a2*b0; acc[2][1] += a2*b1; acc[2][2] += a2*b2; acc[2][3] += a2*b3;
            acc[3][0] += a3*b0; acc[3][1] += a3*b1; acc[3][2] += a3*b2; acc[3][3] += a3*b3;
        }
        __syncthreads();
    }

    int row0 = blockIdx.y * 64 + ty * 4;
    int col0 = blockIdx.x * 64 + tx * 4;
    float bv0 = 0, bv1 = 0, bv2 = 0, bv3 = 0;
    if (bias) { bv0 = bias[col0]; bv1 = bias[col0+1]; bv2 = bias[col0+2]; bv3 = bias[col0+3]; }
    #pragma unroll
    for (int i = 0; i < 4; i++) {
        size_t off = (size_t)(row0 + i) * ldc + col0;
        float4 r = make_float4(0.f, 0.f, 0.f, 0.f);
        if (resid) r = *(const float4*)(resid + off);
        float4 cv;
        cv.x = acc[i][0] + bv0 + r.x;
        cv.y = acc[i][1] + bv1 + r.y;
        cv.z = acc[i][2] + bv2 + r.z;
        cv.w = acc[i][3] + bv3 + r.w;
        *(float4*)(C + off) = cv;
    }
}

// ---------------- Flash-style causal attention ----------------
// q,k,v in (B, T, H*HS) layout; output o same layout (head-concat done by layout).
// Block: 256 threads = 64 query rows x 4 quads (16 dims/cols each).
// grid = (T/64, B*H)
__global__ __launch_bounds__(256) void attn_kernel(
    const float* __restrict__ q, const float* __restrict__ k,
    const float* __restrict__ v, float* __restrict__ o)
{
    int qt = blockIdx.x;               // query tile
    int bh = blockIdx.y;
    int b = bh / NH, h = bh % NH;
    int tid = threadIdx.x;
    int qr = tid >> 2;                 // query row in tile (0..63)
    int quad = tid & 3;                // 16-wide column group

    __shared__ float Qs[64][65], Ks[64][65], Vs[64][65], Ps[64][65];
    __shared__ float red[64][4];
    __shared__ float mrow[64], lrow[64], arow[64];

    size_t base = ((size_t)b * TDIM) * DDIM + (size_t)h * HSZ;
    int q0 = qt * 64;

    // load Q tile (64x64) with float4
    #pragma unroll
    for (int i = 0; i < 4; i++) {
        int flat = tid + i * 256;
        int row = flat >> 4, col = (flat & 15) * 4;
        float4 qv = *(const float4*)(q + base + (size_t)(q0 + row) * DDIM + col);
        Qs[row][col] = qv.x; Qs[row][col+1] = qv.y; Qs[row][col+2] = qv.z; Qs[row][col+3] = qv.w;
    }
    if (tid < 64) { mrow[tid] = -INFINITY; lrow[tid] = 0.f; }
    float o_acc[16];
    #pragma unroll
    for (int d = 0; d < 16; d++) o_acc[d] = 0.f;
    __syncthreads();

    int ntile = qt + 1;
    for (int s = 0; s < ntile; s++) {
        // load K,V tiles
        #pragma unroll
        for (int i = 0; i < 4; i++) {
            int flat = tid + i * 256;
            int row = flat >> 4, col = (flat & 15) * 4;
            float4 kv = *(const float4*)(k + base + (size_t)(s*64 + row) * DDIM + col);
            Ks[row][col] = kv.x; Ks[row][col+1] = kv.y; Ks[row][col+2] = kv.z; Ks[row][col+3] = kv.w;
            float4 vv = *(const float4*)(v + base + (size_t)(s*64 + row) * DDIM + col);
            Vs[row][col] = vv.x; Vs[row][col+1] = vv.y; Vs[row][col+2] = vv.z; Vs[row][col+3] = vv.w;
        }
        __syncthreads();

        // scores: S[qr][quad*16 + j]
        float sv[16];
        int kcb = quad * 16;
        #pragma unroll
        for (int j = 0; j < 16; j++) {
            int kc = kcb + j;
            float acc = 0.f;
            #pragma unroll
            for (int d = 0; d < 64; d++) acc += Qs[qr][d] * Ks[kc][d];
            acc *= SCALE;
            if (s * 64 + kc > q0 + qr) acc = -INFINITY;
            sv[j] = acc;
        }
        // row max
        float lm = sv[0];
        #pragma unroll
        for (int j = 1; j < 16; j++) lm = fmaxf(lm, sv[j]);
        red[qr][quad] = lm;
        __syncthreads();
        if (quad == 0) {
            float tm = fmaxf(fmaxf(red[qr][0], red[qr][1]), fmaxf(red[qr][2], red[qr][3]));
            float mold = mrow[qr];
            float mnew = fmaxf(mold, tm);
            mrow[qr] = mnew;
            arow[qr] = expf(mold - mnew);   // 0 when mold = -inf
        }
        __syncthreads();
        float mnew = mrow[qr];
        float ls = 0.f;
        #pragma unroll
        for (int j = 0; j < 16; j++) {
            float p = expf(sv[j] - mnew);
            Ps[qr][kcb + j] = p;
            ls += p;
        }
        red[qr][quad] = ls;
        float alpha = arow[qr];
        #pragma unroll
        for (int d = 0; d < 16; d++) o_acc[d] *= alpha;
        __syncthreads();
        if (quad == 0)
            lrow[qr] = lrow[qr] * arow[qr] + red[qr][0] + red[qr][1] + red[qr][2] + red[qr][3];

        // O += P @ V  (this thread: row qr, dims quad*16..+16)
        int dbase = quad * 16;
        #pragma unroll 8
        for (int j = 0; j < 64; j++) {
            float p = Ps[qr][j];
            #pragma unroll
            for (int d = 0; d < 16; d++) o_acc[d] += p * Vs[j][dbase + d];
        }
        __syncthreads();   // protects Ks/Vs/Ps for next tile; lrow visible after
    }

    float linv = 1.0f / lrow[qr];
    #pragma unroll
    for (int d = 0; d < 16; d++)
        o[base + (size_t)(q0 + qr) * DDIM + quad * 16 + d] = o_acc[d] * linv;
}

// ---------------- SwiGLU (in-place into first half of u) ----------------
// u: (4096 x 3072); u[:, j] = u[:, j] * silu(u[:, 1536+j]) for j < 1536
__global__ __launch_bounds__(256) void swiglu_kernel(float* __restrict__ u)
{
    int idx = blockIdx.x * 256 + threadIdx.x;
    if (idx >= NROWS * 1536) return;
    int r = idx / 1536, j = idx - r * 1536;
    size_t basep = (size_t)r * 3072;
    float a = u[basep + j];
    float gt = u[basep + 1536 + j];
    u[basep + j] = a * (gt / (1.0f + expf(-gt)));
}

extern "C" void kernel_launch(void* const* d_in, const int* in_sizes, int n_in,
                              void* d_out, int out_size, void* d_ws, size_t ws_size,
                              hipStream_t stream) {
    const float* x  = (const float*)d_in[0];
    const float* Wq = (const float*)d_in[1];
    const float* Wk = (const float*)d_in[2];
    const float* Wv = (const float*)d_in[3];
    const float* Wo = (const float*)d_in[4];
    const float* bo = (const float*)d_in[5];
    const float* W1 = (const float*)d_in[6];
    const float* b1 = (const float*)d_in[7];
    const float* W2 = (const float*)d_in[8];
    const float* b2 = (const float*)d_in[9];
    const float* g1 = (const float*)d_in[10];
    const float* g2 = (const float*)d_in[11];
    float* out = (float*)d_out;
    float* ws  = (float*)d_ws;

    const size_t SZ = (size_t)NROWS * DDIM;   // 3,145,728 floats
    float* hb = ws;            // h (rmsnorm1) -> later attn output
    float* qb = ws + SZ;       // q -> later h2
    float* kb = ws + 2*SZ;
    float* vb = ws + 3*SZ;
    float* ub = ws + 4*SZ;     // u: 4096 x 3072 (4*SZ floats)
    // total ws use: 8*SZ floats = ~100.7 MB

    // 1) h = rmsnorm(x, g1)
    rmsnorm_kernel<<<NROWS, 256, 0, stream>>>(x, g1, hb);

    // 2) q,k,v = h @ W{q,k,v}[head]   -> (B,T,H*HS) layout
    dim3 gQKV(NH, NROWS / 64);
    gemm64<<<gQKV, 256, 0, stream>>>(hb, DDIM, Wq, HSZ, DDIM * HSZ, qb, DDIM, DDIM, nullptr, nullptr);
    gemm64<<<gQKV, 256, 0, stream>>>(hb, DDIM, Wk, HSZ, DDIM * HSZ, kb, DDIM, DDIM, nullptr, nullptr);
    gemm64<<<gQKV, 256, 0, stream>>>(hb, DDIM, Wv, HSZ, DDIM * HSZ, vb, DDIM, DDIM, nullptr, nullptr);

    // 3) attention -> write into hb (h no longer needed)
    attn_kernel<<<dim3(TDIM / 64, 2 * NH), 256, 0, stream>>>(qb, kb, vb, hb);

    // 4) out = x + attn @ Wo + bo
    gemm64<<<dim3(DDIM / 64, NROWS / 64), 256, 0, stream>>>(
        hb, DDIM, Wo, DDIM, 64, out, DDIM, DDIM, bo, x);

    // 5) h2 = rmsnorm(out, g2) -> into qb
    rmsnorm_kernel<<<NROWS, 256, 0, stream>>>(out, g2, qb);

    // 6) u = h2 @ W1 + b1  (4096 x 3072)
    gemm64<<<dim3(3072 / 64, NROWS / 64), 256, 0, stream>>>(
        qb, DDIM, W1, 3072, 64, ub, 3072, DDIM, b1, nullptr);

    // 7) SwiGLU in place: u[:, :1536] = a * silu(gate)
    swiglu_kernel<<<(NROWS * 1536) / 256, 256, 0, stream>>>(ub);

    // 8) out = out + sw @ W2 + b2   (A = ub with lda=3072, K=1536)
    gemm64<<<dim3(DDIM / 64, NROWS / 64), 256, 0, stream>>>(
        ub, 3072, W2, DDIM, 64, out, DDIM, 1536, b2, out);
}

// Round 2
// 1062.564 us; speedup vs baseline: 2.4096x; 2.4096x over previous
//
#include <hip/hip_runtime.h>
#include <math.h>

// Problem constants: B=2, T=2048, D=768, H=12, HS=64, FF=3072, HALF=1536
#define TDIM 2048
#define DDIM 768
#define NH   12
#define HSZ  64
#define NROWS 4096            // B*T
#define EPSV 1e-8f
#define SCALE 0.03608439182435161f   // 768^-0.5  (ref scales by D, not HS)

typedef __bf16 bf16_t;
typedef bf16_t bf16x8 __attribute__((ext_vector_type(8)));
typedef float  floatx4 __attribute__((ext_vector_type(4)));

// ---------------- RMSNorm: out = g * x / (||x||/sqrt(D) + eps) ----------------
__global__ __launch_bounds__(256) void rmsnorm_kernel(
    const float* __restrict__ x, const float* __restrict__ g,
    float* __restrict__ out)
{
    int row = blockIdx.x;
    int tid = threadIdx.x;
    const float* xr = x + (size_t)row * DDIM;
    float v0 = xr[tid], v1 = xr[tid + 256], v2 = xr[tid + 512];
    float s = v0*v0 + v1*v1 + v2*v2;
    #pragma unroll
    for (int off = 32; off > 0; off >>= 1)
        s += __shfl_down(s, off, 64);
    __shared__ float red[4];
    __shared__ float tot;
    if ((tid & 63) == 0) red[tid >> 6] = s;
    __syncthreads();
    if (tid == 0) tot = red[0] + red[1] + red[2] + red[3];
    __syncthreads();
    float rms = sqrtf(tot * (1.0f / DDIM));
    float inv = 1.0f / (rms + EPSV);
    float* orow = out + (size_t)row * DDIM;
    orow[tid]       = g[tid]       * v0 * inv;
    orow[tid + 256] = g[tid + 256] * v1 * inv;
    orow[tid + 512] = g[tid + 512] * v2 * inv;
}

// ---------------- Generic 64x64 tiled fp32 GEMM ----------------
__global__ __launch_bounds__(256) void gemm64(
    const float* __restrict__ A, int lda,
    const float* __restrict__ B, int ldb, int bstride,
    float* __restrict__ C, int ldc, int K,
    const float* __restrict__ bias,
    const float* __restrict__ resid)
{
    __shared__ float As[64][17];   // +1 pad: kills stride-64 bank conflict
    __shared__ float Bs[16][64];
    int tid = threadIdx.x;
    int tx = tid & 15, ty = tid >> 4;
    const float* Ab = A + (size_t)blockIdx.y * 64 * lda;
    const float* Bb = B + (size_t)blockIdx.x * bstride;

    int arow = tid >> 2, acol = (tid & 3) * 4;   // A tile: 64 x 16 via float4
    int brow = tid >> 4, bcol = (tid & 15) * 4;  // B tile: 16 x 64 via float4

    float acc[4][4] = {};
    for (int k0 = 0; k0 < K; k0 += 16) {
        float4 av = *(const float4*)(Ab + (size_t)arow * lda + k0 + acol);
        float4 bv = *(const float4*)(Bb + (size_t)(k0 + brow) * ldb + bcol);
        As[arow][acol+0] = av.x; As[arow][acol+1] = av.y;
        As[arow][acol+2] = av.z; As[arow][acol+3] = av.w;
        *(float4*)&Bs[brow][bcol] = bv;
        __syncthreads();
        #pragma unroll
        for (int kk = 0; kk < 16; kk++) {
            float a0 = As[ty*4+0][kk], a1 = As[ty*4+1][kk];
            float a2 = As[ty*4+2][kk], a3 = As[ty*4+3][kk];
            float b0 = Bs[kk][tx*4+0], b1 = Bs[kk][tx*4+1];
            float b2 = Bs[kk][tx*4+2], b3 = Bs[kk][tx*4+3];
            acc[0][0] += a0*b0; acc[0][1] += a0*b1; acc[0][2] += a0*b2; acc[0][3] += a0*b3;
            acc[1][0] += a1*b0; acc[1][1] += a1*b1; acc[1][2] += a1*b2; acc[1][3] += a1*b3;
            acc[2][0] += a2*b0; acc[2][1] += a2*b1; acc[2][2] += a2*b2; acc[2][3] += a2*b3;
            acc[3][0] += a3*b0; acc[3][1] += a3*b1; acc[3][2] += a3*b2; acc[3][3] += a3*b3;
        }
        __syncthreads();
    }

    int row0 = blockIdx.y * 64 + ty * 4;
    int col0 = blockIdx.x * 64 + tx * 4;
    float bv0 = 0, bv1 = 0, bv2 = 0, bv3 = 0;
    if (bias) { bv0 = bias[col0]; bv1 = bias[col0+1]; bv2 = bias[col0+2]; bv3 = bias[col0+3]; }
    #pragma unroll
    for (int i = 0; i < 4; i++) {
        size_t off = (size_t)(row0 + i) * ldc + col0;
        float4 r = make_float4(0.f, 0.f, 0.f, 0.f);
        if (resid) r = *(const float4*)(resid + off);
        float4 cv;
        cv.x = acc[i][0] + bv0 + r.x;
        cv.y = acc[i][1] + bv1 + r.y;
        cv.z = acc[i][2] + bv2 + r.z;
        cv.w = acc[i][3] + bv3 + r.w;
        *(float4*)(C + off) = cv;
    }
}

// ---------------- MFMA flash attention (bf16 inputs, fp32 accumulate) --------
// grid = (T/64, B*H), block = 256 (4 waves). Wave w owns q rows [q0+16w, q0+16w+16).
// Per 64-col K-tile: S = Q K^T via 4 ntiles x 2 kfrags of mfma_f32_16x16x32_bf16,
// online softmax in registers (shfl_xor over 16-lane col group), P -> LDS (bf16,
// C-layout -> A-layout transform), O += P V with V^T staged in LDS.
__global__ __launch_bounds__(256) void attn_mfma(
    const float* __restrict__ q, const float* __restrict__ k,
    const float* __restrict__ v, float* __restrict__ o)
{
    int qt = blockIdx.x;
    int bh = blockIdx.y;
    int b = bh / NH, h = bh % NH;
    int tid = threadIdx.x;
    int wave = tid >> 6;
    int lane = tid & 63;
    int lrow = lane & 15;      // MFMA m/n lane index
    int quad = lane >> 4;      // MFMA k-group / C-row group

    // pitch 72 bf16 = 144 B (multiple of 16 -> aligned b128 reads)
    __shared__ bf16_t Ks[64][72];      // K tile, row = kcol, col = dim
    __shared__ bf16_t Vt[64][72];      // V tile TRANSPOSED: row = dim, col = kcol
    __shared__ bf16_t Ps[4][16][72];   // per-wave P: row = qrow(0..15), col = kcol

    size_t base = ((size_t)b * TDIM) * DDIM + (size_t)h * HSZ;
    int q0 = qt * 64;
    int qrow_w = q0 + wave * 16;

    // --- Q A-fragments, SCALE folded in. A[m=lrow][k=quad*8+j+32*kf] ---
    bf16x8 qf[2];
    {
        const float* qr = q + base + (size_t)(qrow_w + lrow) * DDIM;
        #pragma unroll
        for (int kf = 0; kf < 2; kf++) {
            int d0 = kf * 32 + quad * 8;
            float4 x0 = *(const float4*)(qr + d0);
            float4 x1 = *(const float4*)(qr + d0 + 4);
            qf[kf][0] = (bf16_t)(x0.x * SCALE); qf[kf][1] = (bf16_t)(x0.y * SCALE);
            qf[kf][2] = (bf16_t)(x0.z * SCALE); qf[kf][3] = (bf16_t)(x0.w * SCALE);
            qf[kf][4] = (bf16_t)(x1.x * SCALE); qf[kf][5] = (bf16_t)(x1.y * SCALE);
            qf[kf][6] = (bf16_t)(x1.z * SCALE); qf[kf][7] = (bf16_t)(x1.w * SCALE);
        }
    }

    floatx4 o_acc[4];
    #pragma unroll
    for (int nt = 0; nt < 4; nt++)
        #pragma unroll
        for (int r = 0; r < 4; r++) o_acc[nt][r] = 0.f;
    float m_r[4] = {-INFINITY, -INFINITY, -INFINITY, -INFINITY};
    float l_r[4] = {0.f, 0.f, 0.f, 0.f};

    int srow = tid >> 4;            // staging: 16 rows per 256-thread pass
    int scol = (tid & 15) * 4;

    for (int s = 0; s <= qt; s++) {
        __syncthreads();   // prior-iter PV reads done before overwriting tiles
        // --- stage K (row-major) and V (transposed) as bf16 ---
        #pragma unroll
        for (int p = 0; p < 4; p++) {
            int r = p * 16 + srow;
            const float* kp = k + base + (size_t)(s * 64 + r) * DDIM + scol;
            float4 kv = *(const float4*)kp;
            Ks[r][scol+0] = (bf16_t)kv.x; Ks[r][scol+1] = (bf16_t)kv.y;
            Ks[r][scol+2] = (bf16_t)kv.z; Ks[r][scol+3] = (bf16_t)kv.w;
            const float* vp = v + base + (size_t)(s * 64 + r) * DDIM + scol;
            float4 vv = *(const float4*)vp;
            Vt[scol+0][r] = (bf16_t)vv.x; Vt[scol+1][r] = (bf16_t)vv.y;
            Vt[scol+2][r] = (bf16_t)vv.z; Vt[scol+3][r] = (bf16_t)vv.w;
        }
        __syncthreads();

        // --- S = Q K^T : C[row=quad*4+r][col=lrow] per ntile ---
        floatx4 sfrag[4];
        #pragma unroll
        for (int nt = 0; nt < 4; nt++) {
            floatx4 acc;
            #pragma unroll
            for (int r = 0; r < 4; r++) acc[r] = 0.f;
            #pragma unroll
            for (int kf = 0; kf < 2; kf++) {
                bf16x8 bfr = *(const bf16x8*)&Ks[nt * 16 + lrow][kf * 32 + quad * 8];
                acc = __builtin_amdgcn_mfma_f32_16x16x32_bf16(qf[kf], bfr, acc, 0, 0, 0);
            }
            sfrag[nt] = acc;
        }

        // --- causal mask (only the diagonal tile needs it) ---
        if (s == qt) {
            #pragma unroll
            for (int nt = 0; nt < 4; nt++)
                #pragma unroll
                for (int r = 0; r < 4; r++) {
                    int col = s * 64 + nt * 16 + lrow;
                    int row = qrow_w + quad * 4 + r;
                    if (col > row) sfrag[nt][r] = -INFINITY;
                }
        }

        // --- online softmax ---
        float tm[4];
        #pragma unroll
        for (int r = 0; r < 4; r++) {
            float mx = sfrag[0][r];
            #pragma unroll
            for (int nt = 1; nt < 4; nt++) mx = fmaxf(mx, sfrag[nt][r]);
            #pragma unroll
            for (int msk = 1; msk < 16; msk <<= 1)
                mx = fmaxf(mx, __shfl_xor(mx, msk, 64));
            tm[r] = mx;
        }
        float alpha[4], ls[4];
        #pragma unroll
        for (int r = 0; r < 4; r++) {
            float mn = fmaxf(m_r[r], tm[r]);
            alpha[r] = __expf(m_r[r] - mn);
            m_r[r] = mn;
            ls[r] = 0.f;
        }
        #pragma unroll
        for (int nt = 0; nt < 4; nt++)
            #pragma unroll
            for (int r = 0; r < 4; r++) {
                float p = __expf(sfrag[nt][r] - m_r[r]);
                sfrag[nt][r] = p;
                ls[r] += p;
                Ps[wave][quad * 4 + r][nt * 16 + lrow] = (bf16_t)p;
            }
        #pragma unroll
        for (int r = 0; r < 4; r++) {
            float sm = ls[r];
            #pragma unroll
            for (int msk = 1; msk < 16; msk <<= 1)
                sm += __shfl_xor(sm, msk, 64);
            l_r[r] = l_r[r] * alpha[r] + sm;
            o_acc[0][r] *= alpha[r]; o_acc[1][r] *= alpha[r];
            o_acc[2][r] *= alpha[r]; o_acc[3][r] *= alpha[r];
        }
        __syncthreads();   // drain P writes before A-frag reads

        // --- O += P V : A = Ps[wave], B = Vt ---
        #pragma unroll
        for (int kf = 0; kf < 2; kf++) {
            bf16x8 af = *(const bf16x8*)&Ps[wave][lrow][kf * 32 + quad * 8];
            #pragma unroll
            for (int nt = 0; nt < 4; nt++) {
                bf16x8 bfr = *(const bf16x8*)&Vt[nt * 16 + lrow][kf * 32 + quad * 8];
                o_acc[nt] = __builtin_amdgcn_mfma_f32_16x16x32_bf16(af, bfr, o_acc[nt], 0, 0, 0);
            }
        }
    }

    // --- epilogue: O /= l, write (C layout: row=quad*4+r, col=lrow) ---
    #pragma unroll
    for (int r = 0; r < 4; r++) {
        float inv = 1.0f / l_r[r];
        size_t rb = base + (size_t)(qrow_w + quad * 4 + r) * DDIM;
        #pragma unroll
        for (int nt = 0; nt < 4; nt++)
            o[rb + nt * 16 + lrow] = o_acc[nt][r] * inv;
    }
}

// ---------------- SwiGLU (in-place into first half of u) ----------------
__global__ __launch_bounds__(256) void swiglu_kernel(float* __restrict__ u)
{
    int idx = blockIdx.x * 256 + threadIdx.x;
    if (idx >= NROWS * 1536) return;
    int r = idx / 1536, j = idx - r * 1536;
    size_t basep = (size_t)r * 3072;
    float a = u[basep + j];
    float gt = u[basep + 1536 + j];
    u[basep + j] = a * (gt / (1.0f + __expf(-gt)));
}

extern "C" void kernel_launch(void* const* d_in, const int* in_sizes, int n_in,
                              void* d_out, int out_size, void* d_ws, size_t ws_size,
                              hipStream_t stream) {
    const float* x  = (const float*)d_in[0];
    const float* Wq = (const float*)d_in[1];
    const float* Wk = (const float*)d_in[2];
    const float* Wv = (const float*)d_in[3];
    const float* Wo = (const float*)d_in[4];
    const float* bo = (const float*)d_in[5];
    const float* W1 = (const float*)d_in[6];
    const float* b1 = (const float*)d_in[7];
    const float* W2 = (const float*)d_in[8];
    const float* b2 = (const float*)d_in[9];
    const float* g1 = (const float*)d_in[10];
    const float* g2 = (const float*)d_in[11];
    float* out = (float*)d_out;
    float* ws  = (float*)d_ws;

    const size_t SZ = (size_t)NROWS * DDIM;   // 3,145,728 floats
    float* hb = ws;            // h (rmsnorm1) -> later attn output
    float* qb = ws + SZ;       // q -> later h2
    float* kb = ws + 2*SZ;
    float* vb = ws + 3*SZ;
    float* ub = ws + 4*SZ;     // u: 4096 x 3072

    // 1) h = rmsnorm(x, g1)
    rmsnorm_kernel<<<NROWS, 256, 0, stream>>>(x, g1, hb);

    // 2) q,k,v = h @ W{q,k,v}[head]   -> (B,T,H*HS) layout
    dim3 gQKV(NH, NROWS / 64);
    gemm64<<<gQKV, 256, 0, stream>>>(hb, DDIM, Wq, HSZ, DDIM * HSZ, qb, DDIM, DDIM, nullptr, nullptr);
    gemm64<<<gQKV, 256, 0, stream>>>(hb, DDIM, Wk, HSZ, DDIM * HSZ, kb, DDIM, DDIM, nullptr, nullptr);
    gemm64<<<gQKV, 256, 0, stream>>>(hb, DDIM, Wv, HSZ, DDIM * HSZ, vb, DDIM, DDIM, nullptr, nullptr);

    // 3) attention -> write into hb (h no longer needed)
    attn_mfma<<<dim3(TDIM / 64, 2 * NH), 256, 0, stream>>>(qb, kb, vb, hb);

    // 4) out = x + attn @ Wo + bo
    gemm64<<<dim3(DDIM / 64, NROWS / 64), 256, 0, stream>>>(
        hb, DDIM, Wo, DDIM, 64, out, DDIM, DDIM, bo, x);

    // 5) h2 = rmsnorm(out, g2) -> into qb
    rmsnorm_kernel<<<NROWS, 256, 0, stream>>>(out, g2, qb);

    // 6) u = h2 @ W1 + b1  (4096 x 3072)
    gemm64<<<dim3(3072 / 64, NROWS / 64), 256, 0, stream>>>(
        qb, DDIM, W1, 3072, 64, ub, 3072, DDIM, b1, nullptr);

    // 7) SwiGLU in place: u[:, :1536] = a * silu(gate)
    swiglu_kernel<<<(NROWS * 1536) / 256, 256, 0, stream>>>(ub);

    // 8) out = out + sw @ W2 + b2   (A = ub with lda=3072, K=1536)
    gemm64<<<dim3(DDIM / 64, NROWS / 64), 256, 0, stream>>>(
        ub, 3072, W2, DDIM, 64, out, DDIM, 1536, b2, out);
}

// Round 3
// 433.109 us; speedup vs baseline: 5.9116x; 2.4533x over previous
//
#include <hip/hip_runtime.h>
#include <math.h>

// Problem constants: B=2, T=2048, D=768, H=12, HS=64, FF=3072, HALF=1536
#define TDIM 2048
#define DDIM 768
#define NH   12
#define NROWS 4096            // B*T
#define EPSV 1e-8f
#define SCALE 0.03608439182435161f   // 768^-0.5  (ref scales by D, not HS)

typedef __bf16 bf16_t;
typedef bf16_t bf16x8 __attribute__((ext_vector_type(8)));
typedef float  floatx4 __attribute__((ext_vector_type(4)));

// async global->LDS, 16B per lane; LDS dest = wave-uniform base + lane*16
__device__ __forceinline__ void glds16(const bf16_t* g, bf16_t* l) {
    __builtin_amdgcn_global_load_lds(
        (const __attribute__((address_space(1))) void*)g,
        (__attribute__((address_space(3))) void*)l, 16, 0, 0);
}

// ---------------- weight repacks (per-call; ~12 MB bf16 total) ----------------
// qkvw_bt[n][k] (2304 x 768): n<768 -> Wq[h=n/64][k][n%64]; then Wk, Wv.
__global__ __launch_bounds__(256) void pack_qkv_bt(
    const float* __restrict__ Wq, const float* __restrict__ Wk,
    const float* __restrict__ Wv, bf16_t* __restrict__ dst)
{
    int k = blockIdx.x * 256 + threadIdx.x;   // 0..767
    int n = blockIdx.y;                       // 0..2303
    int sel = n / 768, nn = n - sel * 768;
    int h = nn >> 6, j = nn & 63;
    const float* W = (sel == 0) ? Wq : (sel == 1) ? Wk : Wv;
    dst[(size_t)n * 768 + k] = (bf16_t)W[(size_t)h * DDIM * 64 + (size_t)k * 64 + j];
}

// dst[n][k] = (bf16) src[k][n];  src is K x N fp32 row-major. grid (K/256, N)
__global__ __launch_bounds__(256) void transpose_bt(
    const float* __restrict__ src, bf16_t* __restrict__ dst, int K, int N)
{
    int k = blockIdx.x * 256 + threadIdx.x;
    int n = blockIdx.y;
    dst[(size_t)n * K + k] = (bf16_t)src[(size_t)k * N + n];
}

// ---------------- RMSNorm -> bf16: out = g * x / (||x||/sqrt(D) + eps) -------
__global__ __launch_bounds__(256) void rmsnorm_bf(
    const float* __restrict__ x, const float* __restrict__ g,
    bf16_t* __restrict__ out)
{
    int row = blockIdx.x;
    int tid = threadIdx.x;
    const float* xr = x + (size_t)row * DDIM;
    float v0 = xr[tid], v1 = xr[tid + 256], v2 = xr[tid + 512];
    float s = v0*v0 + v1*v1 + v2*v2;
    #pragma unroll
    for (int off = 32; off > 0; off >>= 1)
        s += __shfl_down(s, off, 64);
    __shared__ float red[4];
    __shared__ float tot;
    if ((tid & 63) == 0) red[tid >> 6] = s;
    __syncthreads();
    if (tid == 0) tot = red[0] + red[1] + red[2] + red[3];
    __syncthreads();
    float rms = sqrtf(tot * (1.0f / DDIM));
    float inv = 1.0f / (rms + EPSV);
    bf16_t* orow = out + (size_t)row * DDIM;
    orow[tid]       = (bf16_t)(g[tid]       * v0 * inv);
    orow[tid + 256] = (bf16_t)(g[tid + 256] * v1 * inv);
    orow[tid + 512] = (bf16_t)(g[tid + 512] * v2 * inv);
}

// ---------------- bf16 MFMA GEMM (m97 structure) ----------------
// C[M x N] = A[M x K] * BT[N x K]^T. A row-major bf16 (lda == K), BT row-major
// bf16. 128x128 tile, BK=32, 4 waves (2x2, each 64x64 via 4x4 mfma 16x16x32).
// Epilogue: + bias (fp32) + resid (fp32), out to Cf (fp32) or Cb (bf16).
__global__ __launch_bounds__(256) void gemm_bf16(
    const bf16_t* __restrict__ A, const bf16_t* __restrict__ BT, int K,
    float* __restrict__ Cf, bf16_t* __restrict__ Cb, int ldc,
    const float* __restrict__ bias, const float* __restrict__ resid)
{
    __shared__ bf16_t As[128][32];   // 8 KB, row = 64 B
    __shared__ bf16_t Bs[128][32];   // 8 KB, row n of B^T
    int tid = threadIdx.x;
    int wave = tid >> 6, lane = tid & 63;
    int lrow = lane & 15, quad = lane >> 4;
    int wm = wave >> 1, wn = wave & 1;

    int m0 = blockIdx.y * 128;
    int n0 = blockIdx.x * 128;

    // staging: wave stages A rows [wave*32, +32) and B^T rows [wave*32, +32),
    // 2 glds each (16 rows/instr: lane/4 = row, lane%4 = 8-elem k-quarter)
    int srow = lane >> 2, squart = (lane & 3) * 8;
    const bf16_t* Ag = A  + ((size_t)(m0 + wave * 32) + srow) * K + squart;
    const bf16_t* Bg = BT + ((size_t)(n0 + wave * 32) + srow) * K + squart;

    floatx4 acc[4][4];
    #pragma unroll
    for (int i = 0; i < 4; i++)
        #pragma unroll
        for (int j = 0; j < 4; j++)
            #pragma unroll
            for (int r = 0; r < 4; r++) acc[i][j][r] = 0.f;

    for (int k0 = 0; k0 < K; k0 += 32) {
        __syncthreads();
        #pragma unroll
        for (int i = 0; i < 2; i++) {
            glds16(Ag + (size_t)(i * 16) * K + k0, &As[wave * 32 + i * 16][0]);
            glds16(Bg + (size_t)(i * 16) * K + k0, &Bs[wave * 32 + i * 16][0]);
        }
        __syncthreads();   // compiler drains vmcnt(0) before s_barrier

        bf16x8 af[4], bfr[4];
        #pragma unroll
        for (int mt = 0; mt < 4; mt++)
            af[mt] = *(const bf16x8*)&As[wm * 64 + mt * 16 + lrow][quad * 8];
        #pragma unroll
        for (int nt = 0; nt < 4; nt++)
            bfr[nt] = *(const bf16x8*)&Bs[wn * 64 + nt * 16 + lrow][quad * 8];
        #pragma unroll
        for (int mt = 0; mt < 4; mt++)
            #pragma unroll
            for (int nt = 0; nt < 4; nt++)
                acc[mt][nt] = __builtin_amdgcn_mfma_f32_16x16x32_bf16(
                    af[mt], bfr[nt], acc[mt][nt], 0, 0, 0);
    }

    // epilogue: C row = m0+wm*64+mt*16+quad*4+r, col = n0+wn*64+nt*16+lrow
    int crow0 = m0 + wm * 64;
    int ccol0 = n0 + wn * 64;
    #pragma unroll
    for (int nt = 0; nt < 4; nt++) {
        int col = ccol0 + nt * 16 + lrow;
        float bv = bias ? bias[col] : 0.f;
        #pragma unroll
        for (int mt = 0; mt < 4; mt++) {
            #pragma unroll
            for (int r = 0; r < 4; r++) {
                int row = crow0 + mt * 16 + quad * 4 + r;
                size_t off = (size_t)row * ldc + col;
                float val = acc[mt][nt][r] + bv;
                if (resid) val += resid[off];
                if (Cf) Cf[off] = val;
                else    Cb[off] = (bf16_t)val;
            }
        }
    }
}

// ---------------- MFMA flash attention, bf16 I/O ----------------
// qkv: (4096 x 2304) bf16, cols [0,768)=Q, [768,1536)=K, [1536,2304)=V,
// each head h occupying 64 cols at h*64. o: (4096 x 768) bf16.
// grid = (T/64, B*H), block = 256 (4 waves; wave w owns q rows q0+16w..+16).
__global__ __launch_bounds__(256) void attn_mfma(
    const bf16_t* __restrict__ qkv, bf16_t* __restrict__ o)
{
    const int QS = 2304;
    int qt = blockIdx.x;
    int bh = blockIdx.y;
    int b = bh / NH, h = bh % NH;
    int tid = threadIdx.x;
    int wave = tid >> 6, lane = tid & 63;
    int lrow = lane & 15, quad = lane >> 4;

    __shared__ bf16_t Ks[64][72];      // K tile: row = kcol, col = dim
    __shared__ bf16_t Vt[64][72];      // V^T: row = dim, col = kcol
    __shared__ bf16_t Ps[4][16][72];   // per-wave P (A-layout staging)

    size_t rbase = (size_t)b * TDIM;
    int q0 = qt * 64, qrow_w = q0 + wave * 16;

    const bf16_t* qp = qkv + (rbase + qrow_w + lrow) * QS + h * 64;
    bf16x8 qf[2];
    qf[0] = *(const bf16x8*)(qp + quad * 8);
    qf[1] = *(const bf16x8*)(qp + 32 + quad * 8);

    floatx4 o_acc[4];
    #pragma unroll
    for (int nt = 0; nt < 4; nt++)
        #pragma unroll
        for (int r = 0; r < 4; r++) o_acc[nt][r] = 0.f;
    float m_r[4] = {-INFINITY, -INFINITY, -INFINITY, -INFINITY};
    float l_r[4] = {0.f, 0.f, 0.f, 0.f};

    int srow = tid >> 2;            // 0..63 (kcol)
    int scol = (tid & 3) * 16;      // 0,16,32,48 (dim)

    for (int s = 0; s <= qt; s++) {
        __syncthreads();   // prior-iter PV reads done before overwrite
        {
            const bf16_t* kp = qkv + (rbase + s * 64 + srow) * QS + 768 + h * 64 + scol;
            const bf16_t* vp = qkv + (rbase + s * 64 + srow) * QS + 1536 + h * 64 + scol;
            bf16x8 k0 = *(const bf16x8*)kp, k1 = *(const bf16x8*)(kp + 8);
            bf16x8 v0 = *(const bf16x8*)vp, v1 = *(const bf16x8*)(vp + 8);
            *(bf16x8*)&Ks[srow][scol] = k0;
            *(bf16x8*)&Ks[srow][scol + 8] = k1;
            #pragma unroll
            for (int j = 0; j < 8; j++) {
                Vt[scol + j][srow] = v0[j];
                Vt[scol + 8 + j][srow] = v1[j];
            }
        }
        __syncthreads();

        // S = Q K^T (C: row = quad*4+r, col = lrow per 16-col ntile)
        floatx4 sfrag[4];
        #pragma unroll
        for (int nt = 0; nt < 4; nt++) {
            floatx4 a;
            #pragma unroll
            for (int r = 0; r < 4; r++) a[r] = 0.f;
            #pragma unroll
            for (int kf = 0; kf < 2; kf++) {
                bf16x8 bfr = *(const bf16x8*)&Ks[nt * 16 + lrow][kf * 32 + quad * 8];
                a = __builtin_amdgcn_mfma_f32_16x16x32_bf16(qf[kf], bfr, a, 0, 0, 0);
            }
            sfrag[nt] = a;
        }

        // scale + causal mask (diagonal tile only)
        if (s == qt) {
            #pragma unroll
            for (int nt = 0; nt < 4; nt++)
                #pragma unroll
                for (int r = 0; r < 4; r++) {
                    int col = s * 64 + nt * 16 + lrow;
                    int row = qrow_w + quad * 4 + r;
                    sfrag[nt][r] = (col > row) ? -INFINITY : sfrag[nt][r] * SCALE;
                }
        } else {
            #pragma unroll
            for (int nt = 0; nt < 4; nt++)
                #pragma unroll
                for (int r = 0; r < 4; r++) sfrag[nt][r] *= SCALE;
        }

        // online softmax
        float alpha[4];
        #pragma unroll
        for (int r = 0; r < 4; r++) {
            float mx = sfrag[0][r];
            #pragma unroll
            for (int nt = 1; nt < 4; nt++) mx = fmaxf(mx, sfrag[nt][r]);
            #pragma unroll
            for (int msk = 1; msk < 16; msk <<= 1)
                mx = fmaxf(mx, __shfl_xor(mx, msk, 64));
            float mn = fmaxf(m_r[r], mx);
            alpha[r] = __expf(m_r[r] - mn);
            m_r[r] = mn;
        }
        float ls[4] = {0.f, 0.f, 0.f, 0.f};
        #pragma unroll
        for (int nt = 0; nt < 4; nt++)
            #pragma unroll
            for (int r = 0; r < 4; r++) {
                float p = __expf(sfrag[nt][r] - m_r[r]);
                ls[r] += p;
                Ps[wave][quad * 4 + r][nt * 16 + lrow] = (bf16_t)p;
            }
        #pragma unroll
        for (int r = 0; r < 4; r++) {
            float sm = ls[r];
            #pragma unroll
            for (int msk = 1; msk < 16; msk <<= 1)
                sm += __shfl_xor(sm, msk, 64);
            l_r[r] = l_r[r] * alpha[r] + sm;
            o_acc[0][r] *= alpha[r]; o_acc[1][r] *= alpha[r];
            o_acc[2][r] *= alpha[r]; o_acc[3][r] *= alpha[r];
        }
        __syncthreads();   // drain P writes before A-frag reads

        // O += P V  (A = Ps[wave], B^T = Vt)
        #pragma unroll
        for (int kf = 0; kf < 2; kf++) {
            bf16x8 af = *(const bf16x8*)&Ps[wave][lrow][kf * 32 + quad * 8];
            #pragma unroll
            for (int nt = 0; nt < 4; nt++) {
                bf16x8 bfr = *(const bf16x8*)&Vt[nt * 16 + lrow][kf * 32 + quad * 8];
                o_acc[nt] = __builtin_amdgcn_mfma_f32_16x16x32_bf16(af, bfr, o_acc[nt], 0, 0, 0);
            }
        }
    }

    #pragma unroll
    for (int r = 0; r < 4; r++) {
        float inv = 1.0f / l_r[r];
        size_t rb = (rbase + qrow_w + quad * 4 + r) * DDIM + h * 64;
        #pragma unroll
        for (int nt = 0; nt < 4; nt++)
            o[rb + nt * 16 + lrow] = (bf16_t)(o_acc[nt][r] * inv);
    }
}

// ---------------- SwiGLU: sw[r][j] = u[r][j] * silu(u[r][1536+j]) ------------
// u: 4096 x 3072 bf16; sw: 4096 x 1536 bf16. grid 4096 x 192 threads (x8 vec).
__global__ __launch_bounds__(192) void swiglu_bf(
    const bf16_t* __restrict__ u, bf16_t* __restrict__ sw)
{
    int row = blockIdx.x;
    int j0 = threadIdx.x * 8;
    bf16x8 a = *(const bf16x8*)(u + (size_t)row * 3072 + j0);
    bf16x8 g = *(const bf16x8*)(u + (size_t)row * 3072 + 1536 + j0);
    bf16x8 r;
    #pragma unroll
    for (int i = 0; i < 8; i++) {
        float gv = (float)g[i];
        r[i] = (bf16_t)((float)a[i] * (gv / (1.0f + __expf(-gv))));
    }
    *(bf16x8*)(sw + (size_t)row * 1536 + j0) = r;
}

extern "C" void kernel_launch(void* const* d_in, const int* in_sizes, int n_in,
                              void* d_out, int out_size, void* d_ws, size_t ws_size,
                              hipStream_t stream) {
    const float* x  = (const float*)d_in[0];
    const float* Wq = (const float*)d_in[1];
    const float* Wk = (const float*)d_in[2];
    const float* Wv = (const float*)d_in[3];
    const float* Wo = (const float*)d_in[4];
    const float* bo = (const float*)d_in[5];
    const float* W1 = (const float*)d_in[6];
    const float* b1 = (const float*)d_in[7];
    const float* W2 = (const float*)d_in[8];
    const float* b2 = (const float*)d_in[9];
    const float* g1 = (const float*)d_in[10];
    const float* g2 = (const float*)d_in[11];
    float* out = (float*)d_out;
    char* ws = (char*)d_ws;

    // bf16 workspace layout (bytes, 16B-aligned)
    bf16_t* qkvw_bt = (bf16_t*)(ws);                    // 2304x768  = 3,538,944 B
    bf16_t* wo_bt   = (bf16_t*)(ws + 3538944);          // 768x768   = 1,179,648
    bf16_t* w1_bt   = (bf16_t*)(ws + 4718592);          // 3072x768  = 4,718,592
    bf16_t* w2_bt   = (bf16_t*)(ws + 9437184);          // 768x1536  = 2,359,296
    bf16_t* h_bf    = (bf16_t*)(ws + 11796480);         // 4096x768  = 6,291,456
    bf16_t* qkv     = (bf16_t*)(ws + 18087936);         // 4096x2304 = 18,874,368
    bf16_t* attn_bf = (bf16_t*)(ws + 36962304);         // 4096x768  = 6,291,456
    bf16_t* u_bf    = (bf16_t*)(ws + 43253760);         // 4096x3072 = 25,165,824
    bf16_t* sw_bf   = (bf16_t*)(ws + 68419584);         // 4096x1536 = 12,582,912
    // total 81,002,496 B

    // weight repacks (bf16, B^T layouts)
    pack_qkv_bt<<<dim3(3, 2304), 256, 0, stream>>>(Wq, Wk, Wv, qkvw_bt);
    transpose_bt<<<dim3(3, 768),  256, 0, stream>>>(Wo, wo_bt, 768, 768);
    transpose_bt<<<dim3(3, 3072), 256, 0, stream>>>(W1, w1_bt, 768, 3072);
    transpose_bt<<<dim3(6, 768),  256, 0, stream>>>(W2, w2_bt, 1536, 768);

    // 1) h = rmsnorm(x, g1) -> bf16
    rmsnorm_bf<<<NROWS, 256, 0, stream>>>(x, g1, h_bf);

    // 2) qkv = h @ [Wq|Wk|Wv]  (4096 x 2304, bf16 out)
    gemm_bf16<<<dim3(18, 32), 256, 0, stream>>>(
        h_bf, qkvw_bt, 768, nullptr, qkv, 2304, nullptr, nullptr);

    // 3) attention -> attn_bf (4096 x 768 bf16)
    attn_mfma<<<dim3(TDIM / 64, 2 * NH), 256, 0, stream>>>(qkv, attn_bf);

    // 4) out = x + attn @ Wo + bo  (fp32)
    gemm_bf16<<<dim3(6, 32), 256, 0, stream>>>(
        attn_bf, wo_bt, 768, out, nullptr, 768, bo, x);

    // 5) h2 = rmsnorm(out, g2) -> h_bf (reuse)
    rmsnorm_bf<<<NROWS, 256, 0, stream>>>(out, g2, h_bf);

    // 6) u = h2 @ W1 + b1  (4096 x 3072, bf16 out)
    gemm_bf16<<<dim3(24, 32), 256, 0, stream>>>(
        h_bf, w1_bt, 768, nullptr, u_bf, 3072, b1, nullptr);

    // 7) sw = a * silu(gate)  (4096 x 1536 bf16)
    swiglu_bf<<<NROWS, 192, 0, stream>>>(u_bf, sw_bf);

    // 8) out = out + sw @ W2 + b2  (fp32)
    gemm_bf16<<<dim3(6, 32), 256, 0, stream>>>(
        sw_bf, w2_bt, 1536, out, nullptr, 768, b2, out);
}

// Round 4
// 385.945 us; speedup vs baseline: 6.6340x; 1.1222x over previous
//
#include <hip/hip_runtime.h>
#include <math.h>

// Problem constants: B=2, T=2048, D=768, H=12, HS=64, FF=3072, HALF=1536
#define TDIM 2048
#define DDIM 768
#define NH   12
#define NROWS 4096            // B*T
#define EPSV 1e-8f
#define SCALE 0.03608439182435161f   // 768^-0.5  (ref scales by D, not HS)

typedef __bf16 bf16_t;
typedef bf16_t bf16x8 __attribute__((ext_vector_type(8)));
typedef float  floatx4 __attribute__((ext_vector_type(4)));

// async global->LDS, 16B per lane; LDS dest = wave-uniform base + lane*16
__device__ __forceinline__ void glds16(const bf16_t* g, bf16_t* l) {
    __builtin_amdgcn_global_load_lds(
        (const __attribute__((address_space(1))) void*)g,
        (__attribute__((address_space(3))) void*)l, 16, 0, 0);
}

// ------------- coalesced weight repacks (LDS 64x64 tile transpose) -----------
// qkvw_bt[n][k] (2304 x 768): n = sel*768 + h*64 + j -> W{sel}[h][k][j], bf16.
// grid (K/64 = 12, 36 = sel*12 + h), block 256.
__global__ __launch_bounds__(256) void pack_qkv_bt(
    const float* __restrict__ Wq, const float* __restrict__ Wk,
    const float* __restrict__ Wv, bf16_t* __restrict__ dst)
{
    __shared__ float Ts[64][65];
    int k0 = blockIdx.x * 64;
    int y = blockIdx.y;
    int sel = y / 12, h = y - sel * 12;
    const float* W = (sel == 0) ? Wq : (sel == 1) ? Wk : Wv;
    int tid = threadIdx.x;
    int r = tid >> 2, c = (tid & 3) * 16;
    const float* src = W + ((size_t)h * 768 + k0 + r) * 64 + c;
    #pragma unroll
    for (int i = 0; i < 4; i++) {
        float4 t = *(const float4*)(src + i * 4);
        Ts[r][c + i*4 + 0] = t.x; Ts[r][c + i*4 + 1] = t.y;
        Ts[r][c + i*4 + 2] = t.z; Ts[r][c + i*4 + 3] = t.w;
    }
    __syncthreads();
    int j = tid >> 2, kk = (tid & 3) * 16;
    bf16x8 o0, o1;
    #pragma unroll
    for (int i = 0; i < 8; i++) {
        o0[i] = (bf16_t)Ts[kk + i][j];
        o1[i] = (bf16_t)Ts[kk + 8 + i][j];
    }
    bf16_t* d = dst + ((size_t)sel * 768 + h * 64 + j) * 768 + k0 + kk;
    *(bf16x8*)d = o0;
    *(bf16x8*)(d + 8) = o1;
}

// dst[n][k] = (bf16) src[k][n]; src K x N fp32 row-major. grid (K/64, N/64).
__global__ __launch_bounds__(256) void transpose_bt(
    const float* __restrict__ src, bf16_t* __restrict__ dst, int K, int N)
{
    __shared__ float Ts[64][65];
    int k0 = blockIdx.x * 64, n0 = blockIdx.y * 64;
    int tid = threadIdx.x;
    int r = tid >> 2, c = (tid & 3) * 16;
    const float* s = src + (size_t)(k0 + r) * N + n0 + c;
    #pragma unroll
    for (int i = 0; i < 4; i++) {
        float4 t = *(const float4*)(s + i * 4);
        Ts[r][c + i*4 + 0] = t.x; Ts[r][c + i*4 + 1] = t.y;
        Ts[r][c + i*4 + 2] = t.z; Ts[r][c + i*4 + 3] = t.w;
    }
    __syncthreads();
    int n = tid >> 2, kk = (tid & 3) * 16;
    bf16x8 o0, o1;
    #pragma unroll
    for (int i = 0; i < 8; i++) {
        o0[i] = (bf16_t)Ts[kk + i][n];
        o1[i] = (bf16_t)Ts[kk + 8 + i][n];
    }
    bf16_t* d = dst + (size_t)(n0 + n) * K + k0 + kk;
    *(bf16x8*)d = o0;
    *(bf16x8*)(d + 8) = o1;
}

// ---------------- RMSNorm -> bf16 ----------------
__global__ __launch_bounds__(256) void rmsnorm_bf(
    const float* __restrict__ x, const float* __restrict__ g,
    bf16_t* __restrict__ out)
{
    int row = blockIdx.x;
    int tid = threadIdx.x;
    const float* xr = x + (size_t)row * DDIM;
    float v0 = xr[tid], v1 = xr[tid + 256], v2 = xr[tid + 512];
    float s = v0*v0 + v1*v1 + v2*v2;
    #pragma unroll
    for (int off = 32; off > 0; off >>= 1)
        s += __shfl_down(s, off, 64);
    __shared__ float red[4];
    __shared__ float tot;
    if ((tid & 63) == 0) red[tid >> 6] = s;
    __syncthreads();
    if (tid == 0) tot = red[0] + red[1] + red[2] + red[3];
    __syncthreads();
    float rms = sqrtf(tot * (1.0f / DDIM));
    float inv = 1.0f / (rms + EPSV);
    bf16_t* orow = out + (size_t)row * DDIM;
    orow[tid]       = (bf16_t)(g[tid]       * v0 * inv);
    orow[tid + 256] = (bf16_t)(g[tid + 256] * v1 * inv);
    orow[tid + 512] = (bf16_t)(g[tid + 512] * v2 * inv);
}

// ---------------- bf16 MFMA GEMM (m97 structure) ----------------
__global__ __launch_bounds__(256) void gemm_bf16(
    const bf16_t* __restrict__ A, const bf16_t* __restrict__ BT, int K,
    float* __restrict__ Cf, bf16_t* __restrict__ Cb, int ldc,
    const float* __restrict__ bias, const float* __restrict__ resid)
{
    __shared__ bf16_t As[128][32];
    __shared__ bf16_t Bs[128][32];
    int tid = threadIdx.x;
    int wave = tid >> 6, lane = tid & 63;
    int lrow = lane & 15, quad = lane >> 4;
    int wm = wave >> 1, wn = wave & 1;

    int m0 = blockIdx.y * 128;
    int n0 = blockIdx.x * 128;

    int srow = lane >> 2, squart = (lane & 3) * 8;
    const bf16_t* Ag = A  + ((size_t)(m0 + wave * 32) + srow) * K + squart;
    const bf16_t* Bg = BT + ((size_t)(n0 + wave * 32) + srow) * K + squart;

    floatx4 acc[4][4];
    #pragma unroll
    for (int i = 0; i < 4; i++)
        #pragma unroll
        for (int j = 0; j < 4; j++)
            #pragma unroll
            for (int r = 0; r < 4; r++) acc[i][j][r] = 0.f;

    for (int k0 = 0; k0 < K; k0 += 32) {
        __syncthreads();
        #pragma unroll
        for (int i = 0; i < 2; i++) {
            glds16(Ag + (size_t)(i * 16) * K + k0, &As[wave * 32 + i * 16][0]);
            glds16(Bg + (size_t)(i * 16) * K + k0, &Bs[wave * 32 + i * 16][0]);
        }
        __syncthreads();

        bf16x8 af[4], bfr[4];
        #pragma unroll
        for (int mt = 0; mt < 4; mt++)
            af[mt] = *(const bf16x8*)&As[wm * 64 + mt * 16 + lrow][quad * 8];
        #pragma unroll
        for (int nt = 0; nt < 4; nt++)
            bfr[nt] = *(const bf16x8*)&Bs[wn * 64 + nt * 16 + lrow][quad * 8];
        #pragma unroll
        for (int mt = 0; mt < 4; mt++)
            #pragma unroll
            for (int nt = 0; nt < 4; nt++)
                acc[mt][nt] = __builtin_amdgcn_mfma_f32_16x16x32_bf16(
                    af[mt], bfr[nt], acc[mt][nt], 0, 0, 0);
    }

    int crow0 = m0 + wm * 64;
    int ccol0 = n0 + wn * 64;
    #pragma unroll
    for (int nt = 0; nt < 4; nt++) {
        int col = ccol0 + nt * 16 + lrow;
        float bv = bias ? bias[col] : 0.f;
        #pragma unroll
        for (int mt = 0; mt < 4; mt++) {
            #pragma unroll
            for (int r = 0; r < 4; r++) {
                int row = crow0 + mt * 16 + quad * 4 + r;
                size_t off = (size_t)row * ldc + col;
                float val = acc[mt][nt][r] + bv;
                if (resid) val += resid[off];
                if (Cf) Cf[off] = val;
                else    Cb[off] = (bf16_t)val;
            }
        }
    }
}

// ---------------- V transpose: qkv V-part -> vt[bh][dim][t] ----------------
// grid (T/64 = 32, 24), block 256
__global__ __launch_bounds__(256) void vt_kernel(
    const bf16_t* __restrict__ qkv, bf16_t* __restrict__ vt)
{
    __shared__ bf16_t Ts[64][72];
    int t0 = blockIdx.x * 64;
    int bh = blockIdx.y;
    int b = bh / NH, h = bh - b * NH;
    int tid = threadIdx.x;
    int r = tid >> 2, c = (tid & 3) * 16;
    const bf16_t* src = qkv + ((size_t)b * TDIM + t0 + r) * 2304 + 1536 + h * 64 + c;
    *(bf16x8*)&Ts[r][c]     = *(const bf16x8*)src;
    *(bf16x8*)&Ts[r][c + 8] = *(const bf16x8*)(src + 8);
    __syncthreads();
    int d = tid >> 2, tt = (tid & 3) * 16;
    bf16x8 o0, o1;
    #pragma unroll
    for (int i = 0; i < 8; i++) {
        o0[i] = Ts[tt + i][d];
        o1[i] = Ts[tt + 8 + i][d];
    }
    bf16_t* dst = vt + ((size_t)bh * 64 + d) * TDIM + t0 + tt;
    *(bf16x8*)dst = o0;
    *(bf16x8*)(dst + 8) = o1;
}

// ---------------- MFMA flash attention, bf16 I/O, pre-transposed V ----------
// grid = (32, 24); qt = (bx+by)%32 swizzle breaks per-CU qt colocation.
__global__ __launch_bounds__(256) void attn_mfma(
    const bf16_t* __restrict__ qkv, const bf16_t* __restrict__ vt,
    bf16_t* __restrict__ o)
{
    const int QS = 2304;
    int qt = (blockIdx.x + blockIdx.y) & 31;   // load-balance swizzle
    int bh = blockIdx.y;
    int b = bh / NH, h = bh - b * NH;
    int tid = threadIdx.x;
    int wave = tid >> 6, lane = tid & 63;
    int lrow = lane & 15, quad = lane >> 4;

    __shared__ bf16_t Ks[64][72];      // K tile: row = kcol, col = dim
    __shared__ bf16_t Vt[64][72];      // V^T: row = dim, col = kcol
    __shared__ bf16_t Ps[4][16][72];   // per-wave P (A-layout staging)

    size_t rbase = (size_t)b * TDIM;
    int q0 = qt * 64, qrow_w = q0 + wave * 16;

    const bf16_t* qp = qkv + (rbase + qrow_w + lrow) * QS + h * 64;
    bf16x8 qf[2];
    qf[0] = *(const bf16x8*)(qp + quad * 8);
    qf[1] = *(const bf16x8*)(qp + 32 + quad * 8);

    floatx4 o_acc[4];
    #pragma unroll
    for (int nt = 0; nt < 4; nt++)
        #pragma unroll
        for (int r = 0; r < 4; r++) o_acc[nt][r] = 0.f;
    float m_r[4] = {-INFINITY, -INFINITY, -INFINITY, -INFINITY};
    float l_r[4] = {0.f, 0.f, 0.f, 0.f};

    int srow = tid >> 2;            // 0..63
    int scol = (tid & 3) * 16;      // 0,16,32,48

    for (int s = 0; s <= qt; s++) {
        __syncthreads();   // prior-iter PV reads done before overwrite
        {
            // K tile: row = kcol, col = dim (coalesced b128)
            const bf16_t* kp = qkv + (rbase + s * 64 + srow) * QS + 768 + h * 64 + scol;
            *(bf16x8*)&Ks[srow][scol]     = *(const bf16x8*)kp;
            *(bf16x8*)&Ks[srow][scol + 8] = *(const bf16x8*)(kp + 8);
            // V^T tile from pre-transposed vt (coalesced b128, no scalar writes)
            const bf16_t* vp = vt + ((size_t)bh * 64 + srow) * TDIM + s * 64 + scol;
            *(bf16x8*)&Vt[srow][scol]     = *(const bf16x8*)vp;
            *(bf16x8*)&Vt[srow][scol + 8] = *(const bf16x8*)(vp + 8);
        }
        __syncthreads();

        // S = Q K^T (C: row = quad*4+r, col = lrow per 16-col ntile)
        floatx4 sfrag[4];
        #pragma unroll
        for (int nt = 0; nt < 4; nt++) {
            floatx4 a;
            #pragma unroll
            for (int r = 0; r < 4; r++) a[r] = 0.f;
            #pragma unroll
            for (int kf = 0; kf < 2; kf++) {
                bf16x8 bfr = *(const bf16x8*)&Ks[nt * 16 + lrow][kf * 32 + quad * 8];
                a = __builtin_amdgcn_mfma_f32_16x16x32_bf16(qf[kf], bfr, a, 0, 0, 0);
            }
            sfrag[nt] = a;
        }

        // scale + causal mask (diagonal tile only)
        if (s == qt) {
            #pragma unroll
            for (int nt = 0; nt < 4; nt++)
                #pragma unroll
                for (int r = 0; r < 4; r++) {
                    int col = s * 64 + nt * 16 + lrow;
                    int row = qrow_w + quad * 4 + r;
                    sfrag[nt][r] = (col > row) ? -INFINITY : sfrag[nt][r] * SCALE;
                }
        } else {
            #pragma unroll
            for (int nt = 0; nt < 4; nt++)
                #pragma unroll
                for (int r = 0; r < 4; r++) sfrag[nt][r] *= SCALE;
        }

        // online softmax
        float alpha[4];
        #pragma unroll
        for (int r = 0; r < 4; r++) {
            float mx = sfrag[0][r];
            #pragma unroll
            for (int nt = 1; nt < 4; nt++) mx = fmaxf(mx, sfrag[nt][r]);
            #pragma unroll
            for (int msk = 1; msk < 16; msk <<= 1)
                mx = fmaxf(mx, __shfl_xor(mx, msk, 64));
            float mn = fmaxf(m_r[r], mx);
            alpha[r] = __expf(m_r[r] - mn);
            m_r[r] = mn;
        }
        float ls[4] = {0.f, 0.f, 0.f, 0.f};
        #pragma unroll
        for (int nt = 0; nt < 4; nt++)
            #pragma unroll
            for (int r = 0; r < 4; r++) {
                float p = __expf(sfrag[nt][r] - m_r[r]);
                ls[r] += p;
                Ps[wave][quad * 4 + r][nt * 16 + lrow] = (bf16_t)p;
            }
        #pragma unroll
        for (int r = 0; r < 4; r++) {
            float sm = ls[r];
            #pragma unroll
            for (int msk = 1; msk < 16; msk <<= 1)
                sm += __shfl_xor(sm, msk, 64);
            l_r[r] = l_r[r] * alpha[r] + sm;
            o_acc[0][r] *= alpha[r]; o_acc[1][r] *= alpha[r];
            o_acc[2][r] *= alpha[r]; o_acc[3][r] *= alpha[r];
        }
        __syncthreads();   // drain P writes before A-frag reads

        // O += P V  (A = Ps[wave], B^T = Vt)
        #pragma unroll
        for (int kf = 0; kf < 2; kf++) {
            bf16x8 af = *(const bf16x8*)&Ps[wave][lrow][kf * 32 + quad * 8];
            #pragma unroll
            for (int nt = 0; nt < 4; nt++) {
                bf16x8 bfr = *(const bf16x8*)&Vt[nt * 16 + lrow][kf * 32 + quad * 8];
                o_acc[nt] = __builtin_amdgcn_mfma_f32_16x16x32_bf16(af, bfr, o_acc[nt], 0, 0, 0);
            }
        }
    }

    #pragma unroll
    for (int r = 0; r < 4; r++) {
        float inv = 1.0f / l_r[r];
        size_t rb = (rbase + qrow_w + quad * 4 + r) * DDIM + h * 64;
        #pragma unroll
        for (int nt = 0; nt < 4; nt++)
            o[rb + nt * 16 + lrow] = (bf16_t)(o_acc[nt][r] * inv);
    }
}

// ---------------- SwiGLU ----------------
__global__ __launch_bounds__(192) void swiglu_bf(
    const bf16_t* __restrict__ u, bf16_t* __restrict__ sw)
{
    int row = blockIdx.x;
    int j0 = threadIdx.x * 8;
    bf16x8 a = *(const bf16x8*)(u + (size_t)row * 3072 + j0);
    bf16x8 g = *(const bf16x8*)(u + (size_t)row * 3072 + 1536 + j0);
    bf16x8 r;
    #pragma unroll
    for (int i = 0; i < 8; i++) {
        float gv = (float)g[i];
        r[i] = (bf16_t)((float)a[i] * (gv / (1.0f + __expf(-gv))));
    }
    *(bf16x8*)(sw + (size_t)row * 1536 + j0) = r;
}

extern "C" void kernel_launch(void* const* d_in, const int* in_sizes, int n_in,
                              void* d_out, int out_size, void* d_ws, size_t ws_size,
                              hipStream_t stream) {
    const float* x  = (const float*)d_in[0];
    const float* Wq = (const float*)d_in[1];
    const float* Wk = (const float*)d_in[2];
    const float* Wv = (const float*)d_in[3];
    const float* Wo = (const float*)d_in[4];
    const float* bo = (const float*)d_in[5];
    const float* W1 = (const float*)d_in[6];
    const float* b1 = (const float*)d_in[7];
    const float* W2 = (const float*)d_in[8];
    const float* b2 = (const float*)d_in[9];
    const float* g1 = (const float*)d_in[10];
    const float* g2 = (const float*)d_in[11];
    float* out = (float*)d_out;
    char* ws = (char*)d_ws;

    // bf16 workspace layout (bytes, 16B-aligned)
    bf16_t* qkvw_bt = (bf16_t*)(ws);                    // 2304x768  = 3,538,944 B
    bf16_t* wo_bt   = (bf16_t*)(ws + 3538944);          // 768x768   = 1,179,648
    bf16_t* w1_bt   = (bf16_t*)(ws + 4718592);          // 3072x768  = 4,718,592
    bf16_t* w2_bt   = (bf16_t*)(ws + 9437184);          // 768x1536  = 2,359,296
    bf16_t* h_bf    = (bf16_t*)(ws + 11796480);         // 4096x768  = 6,291,456
    bf16_t* qkv     = (bf16_t*)(ws + 18087936);         // 4096x2304 = 18,874,368
    bf16_t* attn_bf = (bf16_t*)(ws + 36962304);         // 4096x768  = 6,291,456
    bf16_t* u_bf    = (bf16_t*)(ws + 43253760);         // 4096x3072 = 25,165,824
    bf16_t* sw_bf   = (bf16_t*)(ws + 68419584);         // 4096x1536 = 12,582,912
    bf16_t* vt      = (bf16_t*)(ws + 81002496);         // 24x64x2048= 6,291,456
    // total 87,293,952 B

    // weight repacks (coalesced LDS tile transpose + bf16 cvt)
    pack_qkv_bt<<<dim3(12, 36), 256, 0, stream>>>(Wq, Wk, Wv, qkvw_bt);
    transpose_bt<<<dim3(12, 12), 256, 0, stream>>>(Wo, wo_bt, 768, 768);
    transpose_bt<<<dim3(12, 48), 256, 0, stream>>>(W1, w1_bt, 768, 3072);
    transpose_bt<<<dim3(24, 12), 256, 0, stream>>>(W2, w2_bt, 1536, 768);

    // 1) h = rmsnorm(x, g1) -> bf16
    rmsnorm_bf<<<NROWS, 256, 0, stream>>>(x, g1, h_bf);

    // 2) qkv = h @ [Wq|Wk|Wv]  (4096 x 2304, bf16 out)
    gemm_bf16<<<dim3(18, 32), 256, 0, stream>>>(
        h_bf, qkvw_bt, 768, nullptr, qkv, 2304, nullptr, nullptr);

    // 2b) vt = V^T per (b,h)
    vt_kernel<<<dim3(32, 24), 256, 0, stream>>>(qkv, vt);

    // 3) attention -> attn_bf
    attn_mfma<<<dim3(32, 24), 256, 0, stream>>>(qkv, vt, attn_bf);

    // 4) out = x + attn @ Wo + bo  (fp32)
    gemm_bf16<<<dim3(6, 32), 256, 0, stream>>>(
        attn_bf, wo_bt, 768, out, nullptr, 768, bo, x);

    // 5) h2 = rmsnorm(out, g2) -> h_bf (reuse)
    rmsnorm_bf<<<NROWS, 256, 0, stream>>>(out, g2, h_bf);

    // 6) u = h2 @ W1 + b1  (4096 x 3072, bf16 out)
    gemm_bf16<<<dim3(24, 32), 256, 0, stream>>>(
        h_bf, w1_bt, 768, nullptr, u_bf, 3072, b1, nullptr);

    // 7) sw = a * silu(gate)
    swiglu_bf<<<NROWS, 192, 0, stream>>>(u_bf, sw_bf);

    // 8) out = out + sw @ W2 + b2  (fp32)
    gemm_bf16<<<dim3(6, 32), 256, 0, stream>>>(
        sw_bf, w2_bt, 1536, out, nullptr, 768, b2, out);
}

// Round 5
// 345.560 us; speedup vs baseline: 7.4094x; 1.1169x over previous
//
#include <hip/hip_runtime.h>
#include <math.h>

// Problem constants: B=2, T=2048, D=768, H=12, HS=64, FF=3072, HALF=1536
#define TDIM 2048
#define DDIM 768
#define NH   12
#define NROWS 4096            // B*T
#define EPSV 1e-8f
#define SCALE 0.03608439182435161f   // 768^-0.5  (ref scales by D, not HS)

typedef __bf16 bf16_t;
typedef bf16_t bf16x8 __attribute__((ext_vector_type(8)));
typedef bf16_t bf16x4 __attribute__((ext_vector_type(4)));
typedef float  floatx4 __attribute__((ext_vector_type(4)));

// async global->LDS, 16B per lane; LDS dest = wave-uniform base + lane*16
__device__ __forceinline__ void glds16(const bf16_t* g, bf16_t* l) {
    __builtin_amdgcn_global_load_lds(
        (const __attribute__((address_space(1))) void*)g,
        (__attribute__((address_space(3))) void*)l, 16, 0, 0);
}

// ------------- coalesced weight repacks (LDS 64x64 tile transpose) -----------
__global__ __launch_bounds__(256) void pack_qkv_bt(
    const float* __restrict__ Wq, const float* __restrict__ Wk,
    const float* __restrict__ Wv, bf16_t* __restrict__ dst)
{
    __shared__ float Ts[64][65];
    int k0 = blockIdx.x * 64;
    int y = blockIdx.y;
    int sel = y / 12, h = y - sel * 12;
    const float* W = (sel == 0) ? Wq : (sel == 1) ? Wk : Wv;
    int tid = threadIdx.x;
    int r = tid >> 2, c = (tid & 3) * 16;
    const float* src = W + ((size_t)h * 768 + k0 + r) * 64 + c;
    #pragma unroll
    for (int i = 0; i < 4; i++) {
        float4 t = *(const float4*)(src + i * 4);
        Ts[r][c + i*4 + 0] = t.x; Ts[r][c + i*4 + 1] = t.y;
        Ts[r][c + i*4 + 2] = t.z; Ts[r][c + i*4 + 3] = t.w;
    }
    __syncthreads();
    int jj = tid >> 2, kk = (tid & 3) * 16;
    bf16x8 o0, o1;
    #pragma unroll
    for (int i = 0; i < 8; i++) {
        o0[i] = (bf16_t)Ts[kk + i][jj];
        o1[i] = (bf16_t)Ts[kk + 8 + i][jj];
    }
    bf16_t* d = dst + ((size_t)sel * 768 + h * 64 + jj) * 768 + k0 + kk;
    *(bf16x8*)d = o0;
    *(bf16x8*)(d + 8) = o1;
}

__global__ __launch_bounds__(256) void transpose_bt(
    const float* __restrict__ src, bf16_t* __restrict__ dst, int K, int N)
{
    __shared__ float Ts[64][65];
    int k0 = blockIdx.x * 64, n0 = blockIdx.y * 64;
    int tid = threadIdx.x;
    int r = tid >> 2, c = (tid & 3) * 16;
    const float* s = src + (size_t)(k0 + r) * N + n0 + c;
    #pragma unroll
    for (int i = 0; i < 4; i++) {
        float4 t = *(const float4*)(s + i * 4);
        Ts[r][c + i*4 + 0] = t.x; Ts[r][c + i*4 + 1] = t.y;
        Ts[r][c + i*4 + 2] = t.z; Ts[r][c + i*4 + 3] = t.w;
    }
    __syncthreads();
    int n = tid >> 2, kk = (tid & 3) * 16;
    bf16x8 o0, o1;
    #pragma unroll
    for (int i = 0; i < 8; i++) {
        o0[i] = (bf16_t)Ts[kk + i][n];
        o1[i] = (bf16_t)Ts[kk + 8 + i][n];
    }
    bf16_t* d = dst + (size_t)(n0 + n) * K + k0 + kk;
    *(bf16x8*)d = o0;
    *(bf16x8*)(d + 8) = o1;
}

// ---------------- RMSNorm -> bf16 ----------------
__global__ __launch_bounds__(256) void rmsnorm_bf(
    const float* __restrict__ x, const float* __restrict__ g,
    bf16_t* __restrict__ out)
{
    int row = blockIdx.x;
    int tid = threadIdx.x;
    const float* xr = x + (size_t)row * DDIM;
    float v0 = xr[tid], v1 = xr[tid + 256], v2 = xr[tid + 512];
    float s = v0*v0 + v1*v1 + v2*v2;
    #pragma unroll
    for (int off = 32; off > 0; off >>= 1)
        s += __shfl_down(s, off, 64);
    __shared__ float red[4];
    __shared__ float tot;
    if ((tid & 63) == 0) red[tid >> 6] = s;
    __syncthreads();
    if (tid == 0) tot = red[0] + red[1] + red[2] + red[3];
    __syncthreads();
    float rms = sqrtf(tot * (1.0f / DDIM));
    float inv = 1.0f / (rms + EPSV);
    bf16_t* orow = out + (size_t)row * DDIM;
    orow[tid]       = (bf16_t)(g[tid]       * v0 * inv);
    orow[tid + 256] = (bf16_t)(g[tid + 256] * v1 * inv);
    orow[tid + 512] = (bf16_t)(g[tid + 512] * v2 * inv);
}

// ---------------- bf16 MFMA GEMM (m97 structure) ----------------
__global__ __launch_bounds__(256) void gemm_bf16(
    const bf16_t* __restrict__ A, const bf16_t* __restrict__ BT, int K,
    float* __restrict__ Cf, bf16_t* __restrict__ Cb, int ldc,
    const float* __restrict__ bias, const float* __restrict__ resid)
{
    __shared__ bf16_t As[128][32];
    __shared__ bf16_t Bs[128][32];
    int tid = threadIdx.x;
    int wave = tid >> 6, lane = tid & 63;
    int lrow = lane & 15, quad = lane >> 4;
    int wm = wave >> 1, wn = wave & 1;

    int m0 = blockIdx.y * 128;
    int n0 = blockIdx.x * 128;

    int srow = lane >> 2, squart = (lane & 3) * 8;
    const bf16_t* Ag = A  + ((size_t)(m0 + wave * 32) + srow) * K + squart;
    const bf16_t* Bg = BT + ((size_t)(n0 + wave * 32) + srow) * K + squart;

    floatx4 acc[4][4];
    #pragma unroll
    for (int i = 0; i < 4; i++)
        #pragma unroll
        for (int jj = 0; jj < 4; jj++)
            #pragma unroll
            for (int r = 0; r < 4; r++) acc[i][jj][r] = 0.f;

    for (int k0 = 0; k0 < K; k0 += 32) {
        __syncthreads();
        #pragma unroll
        for (int i = 0; i < 2; i++) {
            glds16(Ag + (size_t)(i * 16) * K + k0, &As[wave * 32 + i * 16][0]);
            glds16(Bg + (size_t)(i * 16) * K + k0, &Bs[wave * 32 + i * 16][0]);
        }
        __syncthreads();

        bf16x8 af[4], bfr[4];
        #pragma unroll
        for (int mt = 0; mt < 4; mt++)
            af[mt] = *(const bf16x8*)&As[wm * 64 + mt * 16 + lrow][quad * 8];
        #pragma unroll
        for (int nt = 0; nt < 4; nt++)
            bfr[nt] = *(const bf16x8*)&Bs[wn * 64 + nt * 16 + lrow][quad * 8];
        #pragma unroll
        for (int mt = 0; mt < 4; mt++)
            #pragma unroll
            for (int nt = 0; nt < 4; nt++)
                acc[mt][nt] = __builtin_amdgcn_mfma_f32_16x16x32_bf16(
                    af[mt], bfr[nt], acc[mt][nt], 0, 0, 0);
    }

    int crow0 = m0 + wm * 64;
    int ccol0 = n0 + wn * 64;
    #pragma unroll
    for (int nt = 0; nt < 4; nt++) {
        int col = ccol0 + nt * 16 + lrow;
        float bv = bias ? bias[col] : 0.f;
        #pragma unroll
        for (int mt = 0; mt < 4; mt++) {
            #pragma unroll
            for (int r = 0; r < 4; r++) {
                int row = crow0 + mt * 16 + quad * 4 + r;
                size_t off = (size_t)row * ldc + col;
                float val = acc[mt][nt][r] + bv;
                if (resid) val += resid[off];
                if (Cf) Cf[off] = val;
                else    Cb[off] = (bf16_t)val;
            }
        }
    }
}

// ---------------- V transpose: qkv V-part -> vt[bh][dim][t] ----------------
__global__ __launch_bounds__(256) void vt_kernel(
    const bf16_t* __restrict__ qkv, bf16_t* __restrict__ vt)
{
    __shared__ bf16_t Ts[64][72];
    int t0 = blockIdx.x * 64;
    int bh = blockIdx.y;
    int b = bh / NH, h = bh - b * NH;
    int tid = threadIdx.x;
    int r = tid >> 2, c = (tid & 3) * 16;
    const bf16_t* src = qkv + ((size_t)b * TDIM + t0 + r) * 2304 + 1536 + h * 64 + c;
    *(bf16x8*)&Ts[r][c]     = *(const bf16x8*)src;
    *(bf16x8*)&Ts[r][c + 8] = *(const bf16x8*)(src + 8);
    __syncthreads();
    int d = tid >> 2, tt = (tid & 3) * 16;
    bf16x8 o0, o1;
    #pragma unroll
    for (int i = 0; i < 8; i++) {
        o0[i] = Ts[tt + i][d];
        o1[i] = Ts[tt + 8 + i][d];
    }
    bf16_t* dst = vt + ((size_t)bh * 64 + d) * TDIM + t0 + tt;
    *(bf16x8*)dst = o0;
    *(bf16x8*)(dst + 8) = o1;
}

// ---------------- MFMA flash attention, S^T formulation ----------------
// Computes S^T = K Q^T (C: row=kc, col=q), softmax over kc = regs+2 shfls,
// P^T written wave-private as b64, PV as O^T = V^T P^T (b128 A/B frags).
// 1-D grid 768: 3-slot (qt,bh) mapping balances per-CU tile counts (worst 65).
__global__ __launch_bounds__(256) void attn_mfma(
    const bf16_t* __restrict__ qkv, const bf16_t* __restrict__ vt,
    bf16_t* __restrict__ o)
{
    const int QS = 2304;
    int bid = blockIdx.x;
    int j = bid & 255, slot = bid >> 8;
    int qt, bh;
    if (slot == 0)      { qt = j & 31;        bh = j >> 5; }
    else if (slot == 1) { qt = 31 - (j & 31); bh = 8 + (j >> 5); }
    else                { qt = j >> 3;        bh = 16 + (j & 7); }
    int b = bh / NH, h = bh - b * NH;
    int tid = threadIdx.x;
    int wave = tid >> 6, lane = tid & 63;
    int lrow = lane & 15, quad = lane >> 4;

    __shared__ bf16_t Ks[64][72];      // K tile: row = kcol, col = dim
    __shared__ bf16_t Vt[64][72];      // V^T: row = dim, col = kcol
    __shared__ bf16_t Ps[4][16][72];   // per-wave P (row = q, col = kc)

    size_t rbase = (size_t)b * TDIM;
    int q0 = qt * 64, qrow_w = q0 + wave * 16;

    // Q as MFMA B-operand: B[k=d=quad*8+j][n=q=lrow]
    const bf16_t* qp = qkv + (rbase + qrow_w + lrow) * QS + h * 64;
    bf16x8 qf[2];
    qf[0] = *(const bf16x8*)(qp + quad * 8);
    qf[1] = *(const bf16x8*)(qp + 32 + quad * 8);

    floatx4 o_acc[4];   // O^T: (dim = mt*16 + quad*4 + r, q = lrow)
    #pragma unroll
    for (int mt = 0; mt < 4; mt++)
        #pragma unroll
        for (int r = 0; r < 4; r++) o_acc[mt][r] = 0.f;
    float m_r = -INFINITY, l_r = 0.f;

    int srow = tid >> 2;            // 0..63
    int scol = (tid & 3) * 16;      // 0,16,32,48

    for (int s = 0; s <= qt; s++) {
        __syncthreads();   // prior-iter Ks/Vt reads done before overwrite
        {
            const bf16_t* kp = qkv + (rbase + s * 64 + srow) * QS + 768 + h * 64 + scol;
            *(bf16x8*)&Ks[srow][scol]     = *(const bf16x8*)kp;
            *(bf16x8*)&Ks[srow][scol + 8] = *(const bf16x8*)(kp + 8);
            const bf16_t* vp = vt + ((size_t)bh * 64 + srow) * TDIM + s * 64 + scol;
            *(bf16x8*)&Vt[srow][scol]     = *(const bf16x8*)vp;
            *(bf16x8*)&Vt[srow][scol + 8] = *(const bf16x8*)(vp + 8);
        }
        __syncthreads();

        // S^T = K Q^T : C row = kc (nt*16 + quad*4 + r), col = q (lrow)
        floatx4 sfrag[4];
        #pragma unroll
        for (int nt = 0; nt < 4; nt++) {
            floatx4 a;
            #pragma unroll
            for (int r = 0; r < 4; r++) a[r] = 0.f;
            #pragma unroll
            for (int kf = 0; kf < 2; kf++) {
                bf16x8 afr = *(const bf16x8*)&Ks[nt * 16 + lrow][kf * 32 + quad * 8];
                a = __builtin_amdgcn_mfma_f32_16x16x32_bf16(afr, qf[kf], a, 0, 0, 0);
            }
            sfrag[nt] = a;
        }

        // scale + causal mask (diagonal tile only); kc > q masked
        if (s == qt) {
            int qg = qrow_w + lrow;
            #pragma unroll
            for (int nt = 0; nt < 4; nt++)
                #pragma unroll
                for (int r = 0; r < 4; r++) {
                    int kc = s * 64 + nt * 16 + quad * 4 + r;
                    sfrag[nt][r] = (kc > qg) ? -INFINITY : sfrag[nt][r] * SCALE;
                }
        } else {
            #pragma unroll
            for (int nt = 0; nt < 4; nt++)
                #pragma unroll
                for (int r = 0; r < 4; r++) sfrag[nt][r] *= SCALE;
        }

        // online softmax over kc: 15 reg-max + 2 shfls
        float mx = sfrag[0][0];
        #pragma unroll
        for (int nt = 0; nt < 4; nt++)
            #pragma unroll
            for (int r = 0; r < 4; r++) mx = fmaxf(mx, sfrag[nt][r]);
        mx = fmaxf(mx, __shfl_xor(mx, 16, 64));
        mx = fmaxf(mx, __shfl_xor(mx, 32, 64));
        float mn = fmaxf(m_r, mx);
        float alpha = __expf(m_r - mn);
        m_r = mn;

        float ls = 0.f;
        #pragma unroll
        for (int nt = 0; nt < 4; nt++) {
            bf16x4 pv;
            #pragma unroll
            for (int r = 0; r < 4; r++) {
                float p = __expf(sfrag[nt][r] - mn);
                ls += p;
                pv[r] = (bf16_t)p;
            }
            // wave-private P (row = q = lrow, col = kc): one b64 store per nt
            *(bf16x4*)&Ps[wave][lrow][nt * 16 + quad * 4] = pv;
        }
        ls += __shfl_xor(ls, 16, 64);
        ls += __shfl_xor(ls, 32, 64);
        l_r = l_r * alpha + ls;
        #pragma unroll
        for (int mt = 0; mt < 4; mt++)
            #pragma unroll
            for (int r = 0; r < 4; r++) o_acc[mt][r] *= alpha;

        // O^T += V^T P^T  (A = Vt frag b128, B = Ps frag b128; wave-private,
        // same-wave LDS ordering -> no barrier needed)
        #pragma unroll
        for (int kf = 0; kf < 2; kf++) {
            bf16x8 pfr = *(const bf16x8*)&Ps[wave][lrow][kf * 32 + quad * 8];
            #pragma unroll
            for (int mt = 0; mt < 4; mt++) {
                bf16x8 vfr = *(const bf16x8*)&Vt[mt * 16 + lrow][kf * 32 + quad * 8];
                o_acc[mt] = __builtin_amdgcn_mfma_f32_16x16x32_bf16(vfr, pfr, o_acc[mt], 0, 0, 0);
            }
        }
    }

    // epilogue: O = O^T / l; lane holds 4 contiguous dims at q = lrow
    float inv = 1.0f / l_r;
    size_t rb = (rbase + qrow_w + lrow) * DDIM + h * 64;
    #pragma unroll
    for (int mt = 0; mt < 4; mt++) {
        bf16x4 ov;
        #pragma unroll
        for (int r = 0; r < 4; r++) ov[r] = (bf16_t)(o_acc[mt][r] * inv);
        *(bf16x4*)(o + rb + mt * 16 + quad * 4) = ov;
    }
}

// ---------------- SwiGLU ----------------
__global__ __launch_bounds__(192) void swiglu_bf(
    const bf16_t* __restrict__ u, bf16_t* __restrict__ sw)
{
    int row = blockIdx.x;
    int j0 = threadIdx.x * 8;
    bf16x8 a = *(const bf16x8*)(u + (size_t)row * 3072 + j0);
    bf16x8 g = *(const bf16x8*)(u + (size_t)row * 3072 + 1536 + j0);
    bf16x8 r;
    #pragma unroll
    for (int i = 0; i < 8; i++) {
        float gv = (float)g[i];
        r[i] = (bf16_t)((float)a[i] * (gv / (1.0f + __expf(-gv))));
    }
    *(bf16x8*)(sw + (size_t)row * 1536 + j0) = r;
}

extern "C" void kernel_launch(void* const* d_in, const int* in_sizes, int n_in,
                              void* d_out, int out_size, void* d_ws, size_t ws_size,
                              hipStream_t stream) {
    const float* x  = (const float*)d_in[0];
    const float* Wq = (const float*)d_in[1];
    const float* Wk = (const float*)d_in[2];
    const float* Wv = (const float*)d_in[3];
    const float* Wo = (const float*)d_in[4];
    const float* bo = (const float*)d_in[5];
    const float* W1 = (const float*)d_in[6];
    const float* b1 = (const float*)d_in[7];
    const float* W2 = (const float*)d_in[8];
    const float* b2 = (const float*)d_in[9];
    const float* g1 = (const float*)d_in[10];
    const float* g2 = (const float*)d_in[11];
    float* out = (float*)d_out;
    char* ws = (char*)d_ws;

    bf16_t* qkvw_bt = (bf16_t*)(ws);                    // 2304x768
    bf16_t* wo_bt   = (bf16_t*)(ws + 3538944);          // 768x768
    bf16_t* w1_bt   = (bf16_t*)(ws + 4718592);          // 3072x768
    bf16_t* w2_bt   = (bf16_t*)(ws + 9437184);          // 768x1536
    bf16_t* h_bf    = (bf16_t*)(ws + 11796480);         // 4096x768
    bf16_t* qkv     = (bf16_t*)(ws + 18087936);         // 4096x2304
    bf16_t* attn_bf = (bf16_t*)(ws + 36962304);         // 4096x768
    bf16_t* u_bf    = (bf16_t*)(ws + 43253760);         // 4096x3072
    bf16_t* sw_bf   = (bf16_t*)(ws + 68419584);         // 4096x1536
    bf16_t* vt      = (bf16_t*)(ws + 81002496);         // 24x64x2048

    pack_qkv_bt<<<dim3(12, 36), 256, 0, stream>>>(Wq, Wk, Wv, qkvw_bt);
    transpose_bt<<<dim3(12, 12), 256, 0, stream>>>(Wo, wo_bt, 768, 768);
    transpose_bt<<<dim3(12, 48), 256, 0, stream>>>(W1, w1_bt, 768, 3072);
    transpose_bt<<<dim3(24, 12), 256, 0, stream>>>(W2, w2_bt, 1536, 768);

    rmsnorm_bf<<<NROWS, 256, 0, stream>>>(x, g1, h_bf);

    gemm_bf16<<<dim3(18, 32), 256, 0, stream>>>(
        h_bf, qkvw_bt, 768, nullptr, qkv, 2304, nullptr, nullptr);

    vt_kernel<<<dim3(32, 24), 256, 0, stream>>>(qkv, vt);

    attn_mfma<<<768, 256, 0, stream>>>(qkv, vt, attn_bf);

    gemm_bf16<<<dim3(6, 32), 256, 0, stream>>>(
        attn_bf, wo_bt, 768, out, nullptr, 768, bo, x);

    rmsnorm_bf<<<NROWS, 256, 0, stream>>>(out, g2, h_bf);

    gemm_bf16<<<dim3(24, 32), 256, 0, stream>>>(
        h_bf, w1_bt, 768, nullptr, u_bf, 3072, b1, nullptr);

    swiglu_bf<<<NROWS, 192, 0, stream>>>(u_bf, sw_bf);

    gemm_bf16<<<dim3(6, 32), 256, 0, stream>>>(
        sw_bf, w2_bt, 1536, out, nullptr, 768, b2, out);
}

// Round 6
// 266.032 us; speedup vs baseline: 9.6243x; 1.2989x over previous
//
#include <hip/hip_runtime.h>
#include <math.h>

// Problem constants: B=2, T=2048, D=768, H=12, HS=64, FF=3072, HALF=1536
#define TDIM 2048
#define DDIM 768
#define NH   12
#define NROWS 4096            // B*T
#define EPSV 1e-8f
#define SCALE 0.03608439182435161f   // 768^-0.5  (ref scales by D, not HS)

typedef __bf16 bf16_t;
typedef bf16_t bf16x8 __attribute__((ext_vector_type(8)));
typedef bf16_t bf16x4 __attribute__((ext_vector_type(4)));
typedef float  floatx4 __attribute__((ext_vector_type(4)));

// async global->LDS, 16B per lane; LDS dest = wave-uniform base + lane*16
__device__ __forceinline__ void glds16(const bf16_t* g, bf16_t* l) {
    __builtin_amdgcn_global_load_lds(
        (const __attribute__((address_space(1))) void*)g,
        (__attribute__((address_space(3))) void*)l, 16, 0, 0);
}

// ------------- unified weight repack: 64x64 fp32->bf16 tile transpose --------
// 1440 blocks: [0,144) Wo, [144,720) W1, [720,1008) W2, [1008,1440) QKV pack.
__global__ __launch_bounds__(256) void pack_all(
    const float* __restrict__ Wq, const float* __restrict__ Wk,
    const float* __restrict__ Wv, const float* __restrict__ Wo,
    const float* __restrict__ W1, const float* __restrict__ W2,
    bf16_t* __restrict__ qkvw, bf16_t* __restrict__ wo,
    bf16_t* __restrict__ w1, bf16_t* __restrict__ w2)
{
    int bid = blockIdx.x;
    const float* src; bf16_t* dst;
    int srcld, dstld, k0, n0;
    if (bid < 144) {                       // Wo: K=768, N=768 (12x12)
        int kx = bid % 12, nx = bid / 12;
        src = Wo; dst = wo; srcld = 768; dstld = 768; k0 = kx * 64; n0 = nx * 64;
    } else if (bid < 720) {                // W1: K=768, N=3072 (12x48)
        int t = bid - 144; int kx = t % 12, nx = t / 12;
        src = W1; dst = w1; srcld = 3072; dstld = 768; k0 = kx * 64; n0 = nx * 64;
    } else if (bid < 1008) {               // W2: K=1536, N=768 (24x12)
        int t = bid - 720; int kx = t % 24, nx = t / 24;
        src = W2; dst = w2; srcld = 768; dstld = 1536; k0 = kx * 64; n0 = nx * 64;
    } else {                               // QKV: 36 mats (768x64), 12 k-tiles
        int t = bid - 1008; int kx = t % 12, y = t / 12;
        int sel = y / 12, h = y - sel * 12;
        src = ((sel == 0) ? Wq : (sel == 1) ? Wk : Wv) + (size_t)h * 768 * 64;
        dst = qkvw + (size_t)(sel * 768 + h * 64) * 768;
        srcld = 64; dstld = 768; k0 = kx * 64; n0 = 0;
    }
    __shared__ float Ts[64][65];
    int tid = threadIdx.x;
    int r = tid >> 2, c = (tid & 3) * 16;
    const float* s = src + (size_t)(k0 + r) * srcld + n0 + c;
    #pragma unroll
    for (int i = 0; i < 4; i++) {
        float4 t = *(const float4*)(s + i * 4);
        Ts[r][c + i*4 + 0] = t.x; Ts[r][c + i*4 + 1] = t.y;
        Ts[r][c + i*4 + 2] = t.z; Ts[r][c + i*4 + 3] = t.w;
    }
    __syncthreads();
    int n = tid >> 2, kk = (tid & 3) * 16;
    bf16x8 o0, o1;
    #pragma unroll
    for (int i = 0; i < 8; i++) {
        o0[i] = (bf16_t)Ts[kk + i][n];
        o1[i] = (bf16_t)Ts[kk + 8 + i][n];
    }
    bf16_t* d = dst + (size_t)(n0 + n) * dstld + k0 + kk;
    *(bf16x8*)d = o0;
    *(bf16x8*)(d + 8) = o1;
}

// ---------------- RMSNorm -> bf16 ----------------
__global__ __launch_bounds__(256) void rmsnorm_bf(
    const float* __restrict__ x, const float* __restrict__ g,
    bf16_t* __restrict__ out)
{
    int row = blockIdx.x;
    int tid = threadIdx.x;
    const float* xr = x + (size_t)row * DDIM;
    float v0 = xr[tid], v1 = xr[tid + 256], v2 = xr[tid + 512];
    float s = v0*v0 + v1*v1 + v2*v2;
    #pragma unroll
    for (int off = 32; off > 0; off >>= 1)
        s += __shfl_down(s, off, 64);
    __shared__ float red[4];
    __shared__ float tot;
    if ((tid & 63) == 0) red[tid >> 6] = s;
    __syncthreads();
    if (tid == 0) tot = red[0] + red[1] + red[2] + red[3];
    __syncthreads();
    float rms = sqrtf(tot * (1.0f / DDIM));
    float inv = 1.0f / (rms + EPSV);
    bf16_t* orow = out + (size_t)row * DDIM;
    orow[tid]       = (bf16_t)(g[tid]       * v0 * inv);
    orow[tid + 256] = (bf16_t)(g[tid + 256] * v1 * inv);
    orow[tid + 512] = (bf16_t)(g[tid + 512] * v2 * inv);
}

// ---------------- bf16 MFMA GEMM, BK=64 twin-buffer, C^T epilogue ------------
// C[M x N] = A[M x K] * BT[N x K]^T. Tile TM x 128, 4 waves 2x2.
// MFMA computed as D = BT_frag * A_frag -> lane holds 4 consecutive C-cols
// of one C-row => vectorized float4 / bf16x4 stores.
template<int TM>
__global__ __launch_bounds__(256) void gemm_bf16(
    const bf16_t* __restrict__ A, const bf16_t* __restrict__ BT, int K,
    float* __restrict__ Cf, bf16_t* __restrict__ Cb, int ldc,
    const float* __restrict__ bias, const float* __restrict__ resid)
{
    constexpr int MT = TM / 32;           // m-frags per wave (4 or 2)
    __shared__ bf16_t As0[TM][32], As1[TM][32];      // 64B rows (m97 layout)
    __shared__ bf16_t Bs0[128][32], Bs1[128][32];
    int tid = threadIdx.x;
    int wave = tid >> 6, lane = tid & 63;
    int lrow = lane & 15, quad = lane >> 4;
    int wm = wave >> 1, wn = wave & 1;

    int m0 = blockIdx.y * TM;
    int n0 = blockIdx.x * 128;

    int srow = lane >> 2, scol = (lane & 3) * 8;     // 16 rows x 8 elems per glds
    const bf16_t* Ag = A  + ((size_t)m0 + wave * (TM/4) + srow) * K + scol;
    const bf16_t* Bg = BT + ((size_t)n0 + wave * 32 + srow) * K + scol;

    floatx4 acc[MT][4];
    #pragma unroll
    for (int mt = 0; mt < MT; mt++)
        #pragma unroll
        for (int nt = 0; nt < 4; nt++)
            #pragma unroll
            for (int r = 0; r < 4; r++) acc[mt][nt][r] = 0.f;

    for (int k0 = 0; k0 < K; k0 += 64) {
        __syncthreads();
        #pragma unroll
        for (int i = 0; i < TM/64; i++) {            // 2 (TM=128) or 1 (TM=64)
            glds16(Ag + (size_t)(i*16) * K + k0,      &As0[wave*(TM/4) + i*16][0]);
            glds16(Ag + (size_t)(i*16) * K + k0 + 32, &As1[wave*(TM/4) + i*16][0]);
        }
        #pragma unroll
        for (int i = 0; i < 2; i++) {
            glds16(Bg + (size_t)(i*16) * K + k0,      &Bs0[wave*32 + i*16][0]);
            glds16(Bg + (size_t)(i*16) * K + k0 + 32, &Bs1[wave*32 + i*16][0]);
        }
        __syncthreads();

        bf16x8 af0[MT], af1[MT], bf0[4], bf1[4];
        #pragma unroll
        for (int mt = 0; mt < MT; mt++) {
            af0[mt] = *(const bf16x8*)&As0[wm*(TM/2) + mt*16 + lrow][quad * 8];
            af1[mt] = *(const bf16x8*)&As1[wm*(TM/2) + mt*16 + lrow][quad * 8];
        }
        #pragma unroll
        for (int nt = 0; nt < 4; nt++) {
            bf0[nt] = *(const bf16x8*)&Bs0[wn*64 + nt*16 + lrow][quad * 8];
            bf1[nt] = *(const bf16x8*)&Bs1[wn*64 + nt*16 + lrow][quad * 8];
        }
        #pragma unroll
        for (int mt = 0; mt < MT; mt++)
            #pragma unroll
            for (int nt = 0; nt < 4; nt++) {
                acc[mt][nt] = __builtin_amdgcn_mfma_f32_16x16x32_bf16(
                    bf0[nt], af0[mt], acc[mt][nt], 0, 0, 0);
                acc[mt][nt] = __builtin_amdgcn_mfma_f32_16x16x32_bf16(
                    bf1[nt], af1[mt], acc[mt][nt], 0, 0, 0);
            }
    }

    // epilogue (C^T layout): row = m0+wm*(TM/2)+mt*16+lrow,
    //                        col = n0+wn*64+nt*16+quad*4 .. +4
    int crow0 = m0 + wm * (TM/2);
    int ccol0 = n0 + wn * 64;
    #pragma unroll
    for (int mt = 0; mt < MT; mt++) {
        int row = crow0 + mt * 16 + lrow;
        #pragma unroll
        for (int nt = 0; nt < 4; nt++) {
            int col = ccol0 + nt * 16 + quad * 4;
            size_t off = (size_t)row * ldc + col;
            float4 bv = make_float4(0.f, 0.f, 0.f, 0.f);
            if (bias) bv = *(const float4*)(bias + col);
            float4 rs = make_float4(0.f, 0.f, 0.f, 0.f);
            if (resid) rs = *(const float4*)(resid + off);
            floatx4 a = acc[mt][nt];
            if (Cf) {
                float4 v;
                v.x = a[0] + bv.x + rs.x; v.y = a[1] + bv.y + rs.y;
                v.z = a[2] + bv.z + rs.z; v.w = a[3] + bv.w + rs.w;
                *(float4*)(Cf + off) = v;
            } else {
                bf16x4 v;
                v[0] = (bf16_t)(a[0] + bv.x + rs.x);
                v[1] = (bf16_t)(a[1] + bv.y + rs.y);
                v[2] = (bf16_t)(a[2] + bv.z + rs.z);
                v[3] = (bf16_t)(a[3] + bv.w + rs.w);
                *(bf16x4*)(Cb + off) = v;
            }
        }
    }
}

// ---------------- V transpose: qkv V-part -> vt[bh][dim][t] ----------------
__global__ __launch_bounds__(256) void vt_kernel(
    const bf16_t* __restrict__ qkv, bf16_t* __restrict__ vt)
{
    __shared__ bf16_t Ts[64][72];
    int t0 = blockIdx.x * 64;
    int bh = blockIdx.y;
    int b = bh / NH, h = bh - b * NH;
    int tid = threadIdx.x;
    int r = tid >> 2, c = (tid & 3) * 16;
    const bf16_t* src = qkv + ((size_t)b * TDIM + t0 + r) * 2304 + 1536 + h * 64 + c;
    *(bf16x8*)&Ts[r][c]     = *(const bf16x8*)src;
    *(bf16x8*)&Ts[r][c + 8] = *(const bf16x8*)(src + 8);
    __syncthreads();
    int d = tid >> 2, tt = (tid & 3) * 16;
    bf16x8 o0, o1;
    #pragma unroll
    for (int i = 0; i < 8; i++) {
        o0[i] = Ts[tt + i][d];
        o1[i] = Ts[tt + 8 + i][d];
    }
    bf16_t* dst = vt + ((size_t)bh * 64 + d) * TDIM + t0 + tt;
    *(bf16x8*)dst = o0;
    *(bf16x8*)(dst + 8) = o1;
}

// ---------------- MFMA flash attention, S^T formulation ----------------
__global__ __launch_bounds__(256) void attn_mfma(
    const bf16_t* __restrict__ qkv, const bf16_t* __restrict__ vt,
    bf16_t* __restrict__ o)
{
    const int QS = 2304;
    int bid = blockIdx.x;
    int j = bid & 255, slot = bid >> 8;
    int qt, bh;
    if (slot == 0)      { qt = j & 31;        bh = j >> 5; }
    else if (slot == 1) { qt = 31 - (j & 31); bh = 8 + (j >> 5); }
    else                { qt = j >> 3;        bh = 16 + (j & 7); }
    int b = bh / NH, h = bh - b * NH;
    int tid = threadIdx.x;
    int wave = tid >> 6, lane = tid & 63;
    int lrow = lane & 15, quad = lane >> 4;

    __shared__ bf16_t Ks[64][72];      // K tile: row = kcol, col = dim
    __shared__ bf16_t Vt[64][72];      // V^T: row = dim, col = kcol
    __shared__ bf16_t Ps[4][16][72];   // per-wave P (row = q, col = kc)

    size_t rbase = (size_t)b * TDIM;
    int q0 = qt * 64, qrow_w = q0 + wave * 16;

    const bf16_t* qp = qkv + (rbase + qrow_w + lrow) * QS + h * 64;
    bf16x8 qf[2];
    qf[0] = *(const bf16x8*)(qp + quad * 8);
    qf[1] = *(const bf16x8*)(qp + 32 + quad * 8);

    floatx4 o_acc[4];   // O^T: (dim = mt*16 + quad*4 + r, q = lrow)
    #pragma unroll
    for (int mt = 0; mt < 4; mt++)
        #pragma unroll
        for (int r = 0; r < 4; r++) o_acc[mt][r] = 0.f;
    float m_r = -INFINITY, l_r = 0.f;

    int srow = tid >> 2;            // 0..63
    int scol = (tid & 3) * 16;      // 0,16,32,48

    for (int s = 0; s <= qt; s++) {
        __syncthreads();
        {
            const bf16_t* kp = qkv + (rbase + s * 64 + srow) * QS + 768 + h * 64 + scol;
            *(bf16x8*)&Ks[srow][scol]     = *(const bf16x8*)kp;
            *(bf16x8*)&Ks[srow][scol + 8] = *(const bf16x8*)(kp + 8);
            const bf16_t* vp = vt + ((size_t)bh * 64 + srow) * TDIM + s * 64 + scol;
            *(bf16x8*)&Vt[srow][scol]     = *(const bf16x8*)vp;
            *(bf16x8*)&Vt[srow][scol + 8] = *(const bf16x8*)(vp + 8);
        }
        __syncthreads();

        // S^T = K Q^T : C row = kc (nt*16 + quad*4 + r), col = q (lrow)
        floatx4 sfrag[4];
        #pragma unroll
        for (int nt = 0; nt < 4; nt++) {
            floatx4 a;
            #pragma unroll
            for (int r = 0; r < 4; r++) a[r] = 0.f;
            #pragma unroll
            for (int kf = 0; kf < 2; kf++) {
                bf16x8 afr = *(const bf16x8*)&Ks[nt * 16 + lrow][kf * 32 + quad * 8];
                a = __builtin_amdgcn_mfma_f32_16x16x32_bf16(afr, qf[kf], a, 0, 0, 0);
            }
            sfrag[nt] = a;
        }

        if (s == qt) {
            int qg = qrow_w + lrow;
            #pragma unroll
            for (int nt = 0; nt < 4; nt++)
                #pragma unroll
                for (int r = 0; r < 4; r++) {
                    int kc = s * 64 + nt * 16 + quad * 4 + r;
                    sfrag[nt][r] = (kc > qg) ? -INFINITY : sfrag[nt][r] * SCALE;
                }
        } else {
            #pragma unroll
            for (int nt = 0; nt < 4; nt++)
                #pragma unroll
                for (int r = 0; r < 4; r++) sfrag[nt][r] *= SCALE;
        }

        // online softmax over kc: reg-max + 2 shfls
        float mx = sfrag[0][0];
        #pragma unroll
        for (int nt = 0; nt < 4; nt++)
            #pragma unroll
            for (int r = 0; r < 4; r++) mx = fmaxf(mx, sfrag[nt][r]);
        mx = fmaxf(mx, __shfl_xor(mx, 16, 64));
        mx = fmaxf(mx, __shfl_xor(mx, 32, 64));
        float mn = fmaxf(m_r, mx);
        float alpha = __expf(m_r - mn);
        m_r = mn;

        float ls = 0.f;
        #pragma unroll
        for (int nt = 0; nt < 4; nt++) {
            bf16x4 pv;
            #pragma unroll
            for (int r = 0; r < 4; r++) {
                float p = __expf(sfrag[nt][r] - mn);
                ls += p;
                pv[r] = (bf16_t)p;
            }
            *(bf16x4*)&Ps[wave][lrow][nt * 16 + quad * 4] = pv;
        }
        ls += __shfl_xor(ls, 16, 64);
        ls += __shfl_xor(ls, 32, 64);
        l_r = l_r * alpha + ls;
        #pragma unroll
        for (int mt = 0; mt < 4; mt++)
            #pragma unroll
            for (int r = 0; r < 4; r++) o_acc[mt][r] *= alpha;

        // O^T += V^T P^T (wave-private Ps: no barrier needed)
        #pragma unroll
        for (int kf = 0; kf < 2; kf++) {
            bf16x8 pfr = *(const bf16x8*)&Ps[wave][lrow][kf * 32 + quad * 8];
            #pragma unroll
            for (int mt = 0; mt < 4; mt++) {
                bf16x8 vfr = *(const bf16x8*)&Vt[mt * 16 + lrow][kf * 32 + quad * 8];
                o_acc[mt] = __builtin_amdgcn_mfma_f32_16x16x32_bf16(vfr, pfr, o_acc[mt], 0, 0, 0);
            }
        }
    }

    float inv = 1.0f / l_r;
    size_t rb = (rbase + qrow_w + lrow) * DDIM + h * 64;
    #pragma unroll
    for (int mt = 0; mt < 4; mt++) {
        bf16x4 ov;
        #pragma unroll
        for (int r = 0; r < 4; r++) ov[r] = (bf16_t)(o_acc[mt][r] * inv);
        *(bf16x4*)(o + rb + mt * 16 + quad * 4) = ov;
    }
}

// ---------------- SwiGLU ----------------
__global__ __launch_bounds__(192) void swiglu_bf(
    const bf16_t* __restrict__ u, bf16_t* __restrict__ sw)
{
    int row = blockIdx.x;
    int j0 = threadIdx.x * 8;
    bf16x8 a = *(const bf16x8*)(u + (size_t)row * 3072 + j0);
    bf16x8 g = *(const bf16x8*)(u + (size_t)row * 3072 + 1536 + j0);
    bf16x8 r;
    #pragma unroll
    for (int i = 0; i < 8; i++) {
        float gv = (float)g[i];
        r[i] = (bf16_t)((float)a[i] * (gv / (1.0f + __expf(-gv))));
    }
    *(bf16x8*)(sw + (size_t)row * 1536 + j0) = r;
}

extern "C" void kernel_launch(void* const* d_in, const int* in_sizes, int n_in,
                              void* d_out, int out_size, void* d_ws, size_t ws_size,
                              hipStream_t stream) {
    const float* x  = (const float*)d_in[0];
    const float* Wq = (const float*)d_in[1];
    const float* Wk = (const float*)d_in[2];
    const float* Wv = (const float*)d_in[3];
    const float* Wo = (const float*)d_in[4];
    const float* bo = (const float*)d_in[5];
    const float* W1 = (const float*)d_in[6];
    const float* b1 = (const float*)d_in[7];
    const float* W2 = (const float*)d_in[8];
    const float* b2 = (const float*)d_in[9];
    const float* g1 = (const float*)d_in[10];
    const float* g2 = (const float*)d_in[11];
    float* out = (float*)d_out;
    char* ws = (char*)d_ws;

    bf16_t* qkvw_bt = (bf16_t*)(ws);                    // 2304x768
    bf16_t* wo_bt   = (bf16_t*)(ws + 3538944);          // 768x768
    bf16_t* w1_bt   = (bf16_t*)(ws + 4718592);          // 3072x768
    bf16_t* w2_bt   = (bf16_t*)(ws + 9437184);          // 768x1536
    bf16_t* h_bf    = (bf16_t*)(ws + 11796480);         // 4096x768
    bf16_t* qkv     = (bf16_t*)(ws + 18087936);         // 4096x2304
    bf16_t* attn_bf = (bf16_t*)(ws + 36962304);         // 4096x768
    bf16_t* u_bf    = (bf16_t*)(ws + 43253760);         // 4096x3072
    bf16_t* sw_bf   = (bf16_t*)(ws + 68419584);         // 4096x1536
    bf16_t* vt      = (bf16_t*)(ws + 81002496);         // 24x64x2048

    pack_all<<<1440, 256, 0, stream>>>(Wq, Wk, Wv, Wo, W1, W2,
                                       qkvw_bt, wo_bt, w1_bt, w2_bt);

    rmsnorm_bf<<<NROWS, 256, 0, stream>>>(x, g1, h_bf);

    // qkv = h @ [Wq|Wk|Wv]  (4096 x 2304 bf16)
    gemm_bf16<128><<<dim3(18, 32), 256, 0, stream>>>(
        h_bf, qkvw_bt, 768, nullptr, qkv, 2304, nullptr, nullptr);

    vt_kernel<<<dim3(32, 24), 256, 0, stream>>>(qkv, vt);

    attn_mfma<<<768, 256, 0, stream>>>(qkv, vt, attn_bf);

    // out = x + attn @ Wo + bo  (fp32), TM=64 -> 384 blocks
    gemm_bf16<64><<<dim3(6, 64), 256, 0, stream>>>(
        attn_bf, wo_bt, 768, out, nullptr, 768, bo, x);

    rmsnorm_bf<<<NROWS, 256, 0, stream>>>(out, g2, h_bf);

    // u = h2 @ W1 + b1  (4096 x 3072 bf16)
    gemm_bf16<128><<<dim3(24, 32), 256, 0, stream>>>(
        h_bf, w1_bt, 768, nullptr, u_bf, 3072, b1, nullptr);

    swiglu_bf<<<NROWS, 192, 0, stream>>>(u_bf, sw_bf);

    // out = out + sw @ W2 + b2  (fp32), TM=64 -> 384 blocks
    gemm_bf16<64><<<dim3(6, 64), 256, 0, stream>>>(
        sw_bf, w2_bt, 1536, out, nullptr, 768, b2, out);
}